// Round 4
// baseline (309.961 us; speedup 1.0000x reference)
//
#include <hip/hip_runtime.h>
#include <hip/hip_bf16.h>
#include <stdint.h>
#include <math.h>

#define B_ 2
#define S_ 2048
#define H_ 2048
#define NH_ 16
#define NKV_ 4
#define HD_ 128

typedef __bf16 bf16;
typedef __bf16 bf16x8 __attribute__((ext_vector_type(8)));
typedef __bf16 bf16x4 __attribute__((ext_vector_type(4)));
typedef float f32x4 __attribute__((ext_vector_type(4)));

__device__ __forceinline__ void async_copy16(const void* g, void* l) {
  __builtin_amdgcn_global_load_lds(
      (const __attribute__((address_space(1))) void*)(uintptr_t)g,
      (__attribute__((address_space(3))) void*)(uintptr_t)l,
      16, 0, 0);
}

__device__ __forceinline__ f32x4 mfma16(bf16x8 a, bf16x8 b, f32x4 c) {
  return __builtin_amdgcn_mfma_f32_16x16x32_bf16(a, b, c, 0, 0, 0);
}

// ---------------- prep kernels ----------------

__global__ void f32_to_bf16_k(const float* __restrict__ in, bf16* __restrict__ o, int n) {
  int i = (blockIdx.x * 256 + threadIdx.x) * 4;
  if (i >= n) return;
  float4 v = *(const float4*)(in + i);
  bf16x4 r;
  r[0] = (bf16)v.x; r[1] = (bf16)v.y; r[2] = (bf16)v.z; r[3] = (bf16)v.w;
  *(bf16x4*)(o + i) = r;
}

// W: K x N f32 row-major  ->  Wt: N x K bf16 row-major
__global__ void transpose_to_bf16_k(const float* __restrict__ W, bf16* __restrict__ Wt,
                                    int K, int N) {
  __shared__ float tile[32][33];
  int n0 = blockIdx.x * 32, k0 = blockIdx.y * 32;
  int tx = threadIdx.x, ty = threadIdx.y;
#pragma unroll
  for (int j = 0; j < 32; j += 8)
    tile[ty + j][tx] = W[(size_t)(k0 + ty + j) * N + n0 + tx];
  __syncthreads();
#pragma unroll
  for (int j = 0; j < 32; j += 8)
    Wt[(size_t)(n0 + ty + j) * K + k0 + tx] = (bf16)tile[tx][ty + j];
}

__global__ void rope_table_k(float2* __restrict__ tab) {
  int i = blockIdx.x * 256 + threadIdx.x;  // S_*64
  int p = i >> 6, d = i & 63;
  float invf = expf(-((float)(2 * d) / 128.0f) * 9.210340371976184f);
  float fr = (float)p * invf;
  float sv, cv;
  sincosf(fr, &sv, &cv);
  tab[i] = make_float2(cv, sv);
}

__global__ void rope_apply_k(bf16* __restrict__ t, const int* __restrict__ pos_ids,
                             const float2* __restrict__ tab, int hshift, int hmask,
                             float scale) {
  int i = blockIdx.x * 256 + threadIdx.x;
  int d = i & 63;
  int tmp = i >> 6;
  int h = tmp & hmask;
  int row = tmp >> hshift;
  int pos = pos_ids[row];
  float2 cs = tab[pos * 64 + d];
  size_t base = (((size_t)row << hshift) + h) * HD_;
  float a = (float)t[base + d];
  float b = (float)t[base + d + 64];
  t[base + d]      = (bf16)((a * cs.x - b * cs.y) * scale);
  t[base + d + 64] = (bf16)((b * cs.x + a * cs.y) * scale);
}

// ---------------- 8-wave pipelined GEMM: C(MxN) = A(MxK) * Bt(NxK)^T ----------------
// BM=128, BN=256, BK=64; 8 waves (2M x 4N), 64x64 per wave. 3-stage LDS (144 KiB),
// counted vmcnt(6). Per K-tile: 2 phases of {8 ds_read | 3 stage | barrier | lgkm0 |
// 16 MFMA | barrier}. MODE: 0 = bf16 C0, 1 = f32 C0, 2 = QKV routing
// (cols <2048 -> C0=bq stride 2048; <2560 -> C1=bk stride 512; else C2=V^T).

template <int MODE>
__global__ __launch_bounds__(512) void gemm8_k(const bf16* __restrict__ A,
                                               const bf16* __restrict__ Bt,
                                               void* __restrict__ C0,
                                               void* __restrict__ C1,
                                               void* __restrict__ C2,
                                               int M, int N, int K) {
  extern __shared__ __align__(16) char smem[];
  const int tid = threadIdx.x;
  const int lane = tid & 63;
  const int w = tid >> 6;
  const int wm = w >> 2;          // 0..1
  const int wn = w & 3;           // 0..3
  const int g16 = lane >> 4, c16 = lane & 15;
  const int row0 = blockIdx.y * 128;
  const int col0 = blockIdx.x * 256;
  const int srow = tid >> 3;      // staging row within 64-row round
  const int sslot = tid & 7;
  const int ldsw = w * 1024;      // wave-uniform LDS dest piece (HW adds lane*16)

  auto stageA = [&](int s, int kt, int r) {
    int row = r * 64 + srow;
    int ss = sslot ^ (row & 7);
    async_copy16(A + (size_t)(row0 + row) * K + (kt << 6) + ss * 8,
                 smem + s * 49152 + r * 8192 + ldsw);
  };
  auto stageB = [&](int s, int kt, int r) {
    int row = r * 64 + srow;
    int ss = sslot ^ (row & 7);
    async_copy16(Bt + (size_t)(col0 + row) * K + (kt << 6) + ss * 8,
                 smem + s * 49152 + 16384 + r * 8192 + ldsw);
  };

  int offA[2][4], offB[2][4];
#pragma unroll
  for (int ks = 0; ks < 2; ++ks) {
#pragma unroll
    for (int i = 0; i < 4; ++i) {
      int ra = wm * 64 + i * 16 + c16;
      offA[ks][i] = ra * 128 + (((ks * 4 + g16) ^ (ra & 7)) << 4);
      int rb = wn * 64 + i * 16 + c16;
      offB[ks][i] = rb * 128 + (((ks * 4 + g16) ^ (rb & 7)) << 4);
    }
  }

  const f32x4 fz = {0.f, 0.f, 0.f, 0.f};
  f32x4 acc[4][4];
#pragma unroll
  for (int i = 0; i < 4; ++i)
#pragma unroll
    for (int j = 0; j < 4; ++j) acc[i][j] = fz;

  const int nkt = K >> 6;
  // prologue: stage tiles 0 and 1
#pragma unroll
  for (int r = 0; r < 2; ++r) stageA(0, 0, r);
#pragma unroll
  for (int r = 0; r < 4; ++r) stageB(0, 0, r);
#pragma unroll
  for (int r = 0; r < 2; ++r) stageA(1, 1, r);
#pragma unroll
  for (int r = 0; r < 4; ++r) stageB(1, 1, r);
  asm volatile("s_waitcnt vmcnt(6)" ::: "memory");
  __builtin_amdgcn_s_barrier();

  int ct = 0, pt = 2;
  for (int t = 0; t < nkt; ++t) {
    const char* Ab = smem + ct * 49152;
    const char* Bb = Ab + 16384;
    const bool pf = (t + 2 < nkt);
    const int kpf = t + 2;
    bf16x8 af[4], bfr[4];

    // ---- phase 1: ks=0, 16 MFMA ----
#pragma unroll
    for (int i = 0; i < 4; ++i) af[i] = *(const bf16x8*)(Ab + offA[0][i]);
#pragma unroll
    for (int j = 0; j < 4; ++j) bfr[j] = *(const bf16x8*)(Bb + offB[0][j]);
    if (pf) { stageA(pt, kpf, 0); stageA(pt, kpf, 1); stageB(pt, kpf, 0); }
    __builtin_amdgcn_s_barrier();
    asm volatile("s_waitcnt lgkmcnt(0)" ::: "memory");
    __builtin_amdgcn_sched_barrier(0);
    __builtin_amdgcn_s_setprio(1);
#pragma unroll
    for (int i = 0; i < 4; ++i)
#pragma unroll
      for (int j = 0; j < 4; ++j) acc[i][j] = mfma16(af[i], bfr[j], acc[i][j]);
    __builtin_amdgcn_s_setprio(0);
    __builtin_amdgcn_sched_barrier(0);
    __builtin_amdgcn_s_barrier();

    // ---- phase 2: ks=1, 16 MFMA; counted vmcnt for next tile ----
#pragma unroll
    for (int i = 0; i < 4; ++i) af[i] = *(const bf16x8*)(Ab + offA[1][i]);
#pragma unroll
    for (int j = 0; j < 4; ++j) bfr[j] = *(const bf16x8*)(Bb + offB[1][j]);
    if (pf) { stageB(pt, kpf, 1); stageB(pt, kpf, 2); stageB(pt, kpf, 3); }
    if (pf) asm volatile("s_waitcnt vmcnt(6)" ::: "memory");
    else    asm volatile("s_waitcnt vmcnt(0)" ::: "memory");
    __builtin_amdgcn_s_barrier();
    asm volatile("s_waitcnt lgkmcnt(0)" ::: "memory");
    __builtin_amdgcn_sched_barrier(0);
    __builtin_amdgcn_s_setprio(1);
#pragma unroll
    for (int i = 0; i < 4; ++i)
#pragma unroll
      for (int j = 0; j < 4; ++j) acc[i][j] = mfma16(af[i], bfr[j], acc[i][j]);
    __builtin_amdgcn_s_setprio(0);
    __builtin_amdgcn_sched_barrier(0);
    __builtin_amdgcn_s_barrier();

    ct = (ct == 2) ? 0 : ct + 1;
    pt = (pt == 2) ? 0 : pt + 1;
  }

  // C/D mapping: col = lane&15, row = (lane>>4)*4 + reg
#pragma unroll
  for (int i = 0; i < 4; ++i) {
    int gr0 = row0 + wm * 64 + i * 16 + g16 * 4;
#pragma unroll
    for (int j = 0; j < 4; ++j) {
      int gc = col0 + wn * 64 + j * 16 + c16;
      if constexpr (MODE == 2) {
        if (col0 < 2048) {
#pragma unroll
          for (int r = 0; r < 4; ++r)
            ((bf16*)C0)[(size_t)(gr0 + r) * 2048 + gc] = (bf16)acc[i][j][r];
        } else if (col0 < 2560) {
#pragma unroll
          for (int r = 0; r < 4; ++r)
            ((bf16*)C1)[(size_t)(gr0 + r) * 512 + (gc - 2048)] = (bf16)acc[i][j][r];
        } else {
          int dv = gc - 2560;                 // 0..511
          int hkv = dv >> 7, d = dv & 127;
          size_t va = (((size_t)(gr0 >> 11) * NKV_ + hkv) * HD_ + d) * S_ + (gr0 & 2047);
          bf16x4 pk;
#pragma unroll
          for (int r = 0; r < 4; ++r) pk[r] = (bf16)acc[i][j][r];
          *(bf16x4*)((bf16*)C2 + va) = pk;
        }
      } else {
#pragma unroll
        for (int r = 0; r < 4; ++r) {
          if constexpr (MODE == 1)
            ((float*)C0)[(size_t)(gr0 + r) * N + gc] = acc[i][j][r];
          else
            ((bf16*)C0)[(size_t)(gr0 + r) * N + gc] = (bf16)acc[i][j][r];
        }
      }
    }
  }
}

// ---------------- legacy 128^2 GEMM (fallback only) ----------------

template <bool OUT_F32, bool VT_Z1>
__global__ __launch_bounds__(256) void gemm_bt_k(const bf16* __restrict__ A,
                                                 const bf16* __restrict__ Bt0,
                                                 const bf16* __restrict__ Bt1,
                                                 void* __restrict__ C0, void* __restrict__ C1,
                                                 int M, int N, int K) {
  const bf16* __restrict__ Bt = (blockIdx.z == 0) ? Bt0 : Bt1;
  void* C = (blockIdx.z == 0) ? C0 : C1;
  __shared__ __align__(16) bf16 As[128 * 64];
  __shared__ __align__(16) bf16 Bs[128 * 64];
  const int tid = threadIdx.x;
  const int lane = tid & 63;
  const int w = tid >> 6;
  const int wm = w >> 1, wn = w & 1;
  const int g16 = lane >> 4, c16 = lane & 15;
  const int row0 = blockIdx.y * 128;
  const int col0 = blockIdx.x * 128;
  const int sr = lane >> 3;
  const int st = lane & 7;
  const int ss = st ^ sr;

  const f32x4 fz = {0.f, 0.f, 0.f, 0.f};
  f32x4 acc[4][4];
#pragma unroll
  for (int i = 0; i < 4; ++i)
#pragma unroll
    for (int j = 0; j < 4; ++j) acc[i][j] = fz;

  const int nkt = K >> 6;
  for (int kt = 0; kt < nkt; ++kt) {
    const int k0 = kt << 6;
    __syncthreads();
#pragma unroll
    for (int c = 0; c < 4; ++c) {
      int rbase = w * 32 + c * 8;
      async_copy16(A + (size_t)(row0 + rbase + sr) * K + k0 + ss * 8,
                   (char*)As + rbase * 128);
      async_copy16(Bt + (size_t)(col0 + rbase + sr) * K + k0 + ss * 8,
                   (char*)Bs + rbase * 128);
    }
    __syncthreads();
#pragma unroll
    for (int ks = 0; ks < 2; ++ks) {
      bf16x8 af[4], bfr[4];
#pragma unroll
      for (int t = 0; t < 4; ++t) {
        int ra = wm * 64 + t * 16 + c16;
        af[t] = *(const bf16x8*)((const char*)As + ra * 128 + (((ks * 4 + g16) ^ (ra & 7)) << 4));
        int rb = wn * 64 + t * 16 + c16;
        bfr[t] = *(const bf16x8*)((const char*)Bs + rb * 128 + (((ks * 4 + g16) ^ (rb & 7)) << 4));
      }
#pragma unroll
      for (int i = 0; i < 4; ++i)
#pragma unroll
        for (int j = 0; j < 4; ++j) acc[i][j] = mfma16(af[i], bfr[j], acc[i][j]);
    }
  }

  const bool vt = VT_Z1 && (blockIdx.z == 1);
#pragma unroll
  for (int i = 0; i < 4; ++i) {
    int gr0 = row0 + wm * 64 + i * 16 + g16 * 4;
#pragma unroll
    for (int j = 0; j < 4; ++j) {
      int gc = col0 + wn * 64 + j * 16 + c16;
      if (vt) {
        size_t va = ((size_t)((gr0 >> 11) * NKV_ + (gc >> 7)) * HD_ + (gc & 127)) * S_ + (gr0 & 2047);
        bf16x4 pk;
#pragma unroll
        for (int r = 0; r < 4; ++r) pk[r] = (bf16)acc[i][j][r];
        *(bf16x4*)((bf16*)C + va) = pk;
      } else {
#pragma unroll
        for (int r = 0; r < 4; ++r) {
          if constexpr (OUT_F32)
            ((float*)C)[(size_t)(gr0 + r) * N + gc] = acc[i][j][r];
          else
            ((bf16*)C)[(size_t)(gr0 + r) * N + gc] = (bf16)acc[i][j][r];
        }
      }
    }
  }
}

// ---------------- flash attention v3 (causal, GQA) ----------------
// QBLK=128, 2 waves x 64 q-rows each, KVBLK=64. Swapped QK^T (mfma(K,Q)) with
// permuted K rows so P is fully in-lane for PV. Q + offsets hoisted to registers;
// K/V^T double-buffered LDS via global_load_lds. exp2-domain softmax + defer-max.
// grid = 512 blocks of 128 threads, heavy-qb-first remap.

__global__ __launch_bounds__(128, 1) void attn_fwd_k(const bf16* __restrict__ Qg,
                                                     const bf16* __restrict__ Kg,
                                                     const bf16* __restrict__ VTg,
                                                     bf16* __restrict__ Og) {
  __shared__ __align__(16) bf16 Ks[2][64 * 128];   // rows 256B (16 slots), swz slot^(row&7)
  __shared__ __align__(16) bf16 Vt[2][128 * 64];   // rows 128B (8 slots),  swz slot^(row&7)

  const int tid = threadIdx.x;
  const int lane = tid & 63;
  const int w = tid >> 6;          // 0..1
  const int g16 = lane >> 4;
  const int c16 = lane & 15;

  int bid = blockIdx.x;
  int rr_ = bid >> 5, bh = bid & 31;
  int qb = (rr_ < 8) ? (15 - rr_) : (rr_ - 8);
  const int b = bh >> 4;
  const int h = bh & 15;
  const int hkv = h >> 2;
  const int q0 = qb * 128;
  const int qw = q0 + w * 64;      // wave covers q rows [qw, qw+64)

  // Q fragments in registers: qf[nq][ksq]
  bf16x8 qf[4][4];
#pragma unroll
  for (int nq = 0; nq < 4; ++nq)
#pragma unroll
    for (int ksq = 0; ksq < 4; ++ksq)
      qf[nq][ksq] = *(const bf16x8*)(Qg + ((size_t)(b * S_ + qw + nq * 16 + c16) * NH_ + h) * HD_ + (ksq * 4 + g16) * 8);

  // hoisted LDS fragment offsets
  int kfo[4][4];
#pragma unroll
  for (int ksq = 0; ksq < 4; ++ksq)
#pragma unroll
    for (int mt = 0; mt < 4; ++mt) {
      int gp = c16 >> 2, rp = c16 & 3;
      int blk = 8 * (mt >> 1) + 2 * gp + ((mt & 1) ^ (gp & 1));
      int row = blk * 4 + rp;
      kfo[ksq][mt] = row * 256 + (((ksq * 4 + g16) ^ (row & 7)) << 4);
    }
  int vfo[2][8];
#pragma unroll
  for (int ks = 0; ks < 2; ++ks)
#pragma unroll
    for (int dt = 0; dt < 8; ++dt) {
      int rv = dt * 16 + c16;
      vfo[ks][dt] = rv * 128 + (((ks * 4 + g16) ^ (rv & 7)) << 4);
    }

  float m_run[4] = {-1e30f, -1e30f, -1e30f, -1e30f};
  float l_run[4] = {0.f, 0.f, 0.f, 0.f};
  const f32x4 fz = {0.f, 0.f, 0.f, 0.f};
  f32x4 acc[4][8];
#pragma unroll
  for (int nq = 0; nq < 4; ++nq)
#pragma unroll
    for (int dt = 0; dt < 8; ++dt) acc[nq][dt] = fz;

  const size_t kbase = ((size_t)b * S_ * NKV_ + hkv) * HD_;
  const size_t vbase = ((size_t)(b * NKV_ + hkv)) * HD_ * S_;

  auto stage = [&](int buf, int kv0) {
#pragma unroll
    for (int rd = 0; rd < 8; ++rd) {
      int idx = rd * 128 + tid;          // 0..1023
      int row = idx >> 4;
      int ssl = (idx & 15) ^ (row & 7);
      async_copy16(Kg + kbase + (size_t)(kv0 + row) * (NKV_ * HD_) + ssl * 8,
                   (char*)&Ks[buf][0] + (rd * 128 + w * 64) * 16);
    }
#pragma unroll
    for (int rd = 0; rd < 8; ++rd) {
      int idx = rd * 128 + tid;
      int row = idx >> 3;
      int ssl = (idx & 7) ^ (row & 7);
      async_copy16(VTg + vbase + (size_t)row * S_ + kv0 + ssl * 8,
                   (char*)&Vt[buf][0] + (rd * 128 + w * 64) * 16);
    }
  };

  const int ntiles = 2 * qb + 2;
  stage(0, 0);
  int cur = 0;

  for (int t = 0; t < ntiles; ++t) {
    __syncthreads();  // drains stage(t) vmcnt; separates compute(t-1) from stage(t+1)
    if (t + 1 < ntiles) stage(cur ^ 1, (t + 1) * 64);
    const int kv0 = t * 64;

    if (kv0 <= qw + 63) {
      const char* KsC = (const char*)&Ks[cur][0];
      const char* VtC = (const char*)&Vt[cur][0];

      // ---- swapped QK^T: D[m=kv(perm)][n=q] ----
      f32x4 sc[4][4];
#pragma unroll
      for (int nq = 0; nq < 4; ++nq)
#pragma unroll
        for (int mt = 0; mt < 4; ++mt) sc[nq][mt] = fz;

#pragma unroll
      for (int ksq = 0; ksq < 4; ++ksq) {
        bf16x8 kf[4];
#pragma unroll
        for (int mt = 0; mt < 4; ++mt)
          kf[mt] = *(const bf16x8*)(KsC + kfo[ksq][mt]);
#pragma unroll
        for (int nq = 0; nq < 4; ++nq)
#pragma unroll
          for (int mt = 0; mt < 4; ++mt)
            sc[nq][mt] = mfma16(kf[mt], qf[nq][ksq], sc[nq][mt]);
      }

      // ---- causal mask (kv of sc[nq][mt][r] = blk(mt,g16)*4+r) ----
      if (kv0 + 63 > qw) {
#pragma unroll
        for (int nq = 0; nq < 4; ++nq) {
          int qa = qw + nq * 16 + c16;
#pragma unroll
          for (int mt = 0; mt < 4; ++mt) {
            int blk = 8 * (mt >> 1) + 2 * g16 + ((mt & 1) ^ (g16 & 1));
#pragma unroll
            for (int r = 0; r < 4; ++r) {
              int ka = kv0 + blk * 4 + r;
              if (ka > qa) sc[nq][mt][r] = -1e30f;
            }
          }
        }
      }

      // ---- online softmax (base-2) with defer-max ----
      float mx[4];
#pragma unroll
      for (int nq = 0; nq < 4; ++nq) {
        float v = sc[nq][0][0];
#pragma unroll
        for (int mt = 0; mt < 4; ++mt)
#pragma unroll
          for (int r = 0; r < 4; ++r) v = fmaxf(v, sc[nq][mt][r]);
        v = fmaxf(v, __shfl_xor(v, 16));
        v = fmaxf(v, __shfl_xor(v, 32));
        mx[nq] = v;
      }
      bool need = (mx[0] > m_run[0] + 8.f) || (mx[1] > m_run[1] + 8.f) ||
                  (mx[2] > m_run[2] + 8.f) || (mx[3] > m_run[3] + 8.f);
      if (__any(need)) {
#pragma unroll
        for (int nq = 0; nq < 4; ++nq) {
          float mn = fmaxf(m_run[nq], mx[nq]);
          float corr = exp2f(m_run[nq] - mn);
          m_run[nq] = mn;
          l_run[nq] *= corr;
#pragma unroll
          for (int dt = 0; dt < 8; ++dt) acc[nq][dt] *= corr;
        }
      }
#pragma unroll
      for (int nq = 0; nq < 4; ++nq) {
        float sum = 0.f;
#pragma unroll
        for (int mt = 0; mt < 4; ++mt)
#pragma unroll
          for (int r = 0; r < 4; ++r) {
            float p = exp2f(sc[nq][mt][r] - m_run[nq]);
            sc[nq][mt][r] = p;
            sum += p;
          }
        sum += __shfl_xor(sum, 16);
        sum += __shfl_xor(sum, 32);
        l_run[nq] += sum;
      }

      // ---- P -> bf16 fragments, fully in-lane ----
      bf16x8 pa[4][2];
#pragma unroll
      for (int nq = 0; nq < 4; ++nq)
#pragma unroll
        for (int ks = 0; ks < 2; ++ks) {
          f32x4 sA = (g16 & 1) ? sc[nq][2 * ks + 1] : sc[nq][2 * ks];
          f32x4 sB = (g16 & 1) ? sc[nq][2 * ks] : sc[nq][2 * ks + 1];
          bf16x8 tf;
          tf[0] = (bf16)sA[0]; tf[1] = (bf16)sA[1]; tf[2] = (bf16)sA[2]; tf[3] = (bf16)sA[3];
          tf[4] = (bf16)sB[0]; tf[5] = (bf16)sB[1]; tf[6] = (bf16)sB[2]; tf[7] = (bf16)sB[3];
          pa[nq][ks] = tf;
        }

      // ---- PV: D[m=d][n=q] += V^T-frag x P-frag ----
#pragma unroll
      for (int ks = 0; ks < 2; ++ks)
#pragma unroll
        for (int dt = 0; dt < 8; ++dt) {
          bf16x8 vf = *(const bf16x8*)(VtC + vfo[ks][dt]);
#pragma unroll
          for (int nq = 0; nq < 4; ++nq)
            acc[nq][dt] = mfma16(vf, pa[nq][ks], acc[nq][dt]);
        }
    }
    cur ^= 1;
  }

  // ---- epilogue: O[q][d] = acc^T / l, packed 8B stores ----
#pragma unroll
  for (int nq = 0; nq < 4; ++nq) {
    float inv = 1.0f / l_run[nq];
    size_t base = ((size_t)(b * S_ + qw + nq * 16 + c16) * NH_ + h) * HD_ + g16 * 4;
#pragma unroll
    for (int dt = 0; dt < 8; ++dt) {
      bf16x4 ov;
#pragma unroll
      for (int r = 0; r < 4; ++r) ov[r] = (bf16)(acc[nq][dt][r] * inv);
      *(bf16x4*)(Og + base + dt * 16) = ov;
    }
  }
}

// ---------------- launcher ----------------

extern "C" void kernel_launch(void* const* d_in, const int* in_sizes, int n_in,
                              void* d_out, int out_size, void* d_ws, size_t ws_size,
                              hipStream_t stream) {
  const float* x  = (const float*)d_in[0];
  const int* pos  = (const int*)d_in[2];
  const float* Wq = (const float*)d_in[3];
  const float* Wk = (const float*)d_in[4];
  const float* Wv = (const float*)d_in[5];
  const float* Wo = (const float*)d_in[6];

  char* ws = (char*)d_ws;
  size_t off = 0;
  auto alloc = [&](size_t bytes) -> char* {
    char* p = ws + off;
    off += (bytes + 255) & ~(size_t)255;
    return p;
  };
  const size_t rows = (size_t)B_ * S_;
  bf16* xb    = (bf16*)alloc(rows * H_ * 2);
  bf16* bq    = (bf16*)alloc(rows * (NH_ * HD_) * 2);
  bf16* batt  = (bf16*)alloc(rows * (NH_ * HD_) * 2);
  bf16* WqkvT = (bf16*)alloc((size_t)3072 * H_ * 2);   // rows: Wq 0..2047 | Wk ..2559 | Wv ..3071
  bf16* WoT   = (bf16*)alloc((size_t)H_ * H_ * 2);
  bf16* bk    = (bf16*)alloc(rows * (NKV_ * HD_) * 2);
  bf16* VT    = (bf16*)alloc(rows * (NKV_ * HD_) * 2); // [b][hkv][d][S]
  float2* tab = (float2*)alloc((size_t)S_ * 64 * sizeof(float2));

  bf16* WqT = WqkvT;
  bf16* WkT = WqkvT + (size_t)2048 * H_;
  bf16* WvT = WqkvT + (size_t)2560 * H_;

  // enable 144 KiB dynamic LDS for the 8-wave GEMM (fallback to legacy if refused)
  auto* fqkv = gemm8_k<2>;
  auto* fo   = gemm8_k<1>;
  const int dynlds = 3 * 49152;
  bool big =
      (hipFuncSetAttribute((const void*)fqkv, hipFuncAttributeMaxDynamicSharedMemorySize, dynlds) == hipSuccess) &&
      (hipFuncSetAttribute((const void*)fo, hipFuncAttributeMaxDynamicSharedMemorySize, dynlds) == hipSuccess);

  // prep
  f32_to_bf16_k<<<(rows * H_) / (256 * 4), 256, 0, stream>>>(x, xb, rows * H_);
  transpose_to_bf16_k<<<dim3(H_ / 32, H_ / 32), dim3(32, 8), 0, stream>>>(Wq, WqT, H_, NH_ * HD_);
  transpose_to_bf16_k<<<dim3((NKV_ * HD_) / 32, H_ / 32), dim3(32, 8), 0, stream>>>(Wk, WkT, H_, NKV_ * HD_);
  transpose_to_bf16_k<<<dim3((NKV_ * HD_) / 32, H_ / 32), dim3(32, 8), 0, stream>>>(Wv, WvT, H_, NKV_ * HD_);
  transpose_to_bf16_k<<<dim3(H_ / 32, H_ / 32), dim3(32, 8), 0, stream>>>(Wo, WoT, H_, H_);
  rope_table_k<<<(S_ * 64) / 256, 256, 0, stream>>>(tab);

  // fused QKV projection (12 col-blocks: 8 Q, 2 K, 2 V^T)
  if (big) {
    gemm8_k<2><<<dim3(12, 32), 512, dynlds, stream>>>(xb, WqkvT, bq, bk, VT, 4096, 3072, 2048);
  } else {
    gemm_bt_k<false, false><<<dim3(16, 32, 1), 256, 0, stream>>>(xb, WqT, WqT, bq, bq, 4096, 2048, 2048);
    gemm_bt_k<false, true><<<dim3(4, 32, 2), 256, 0, stream>>>(xb, WkT, WvT, bk, VT, 4096, 512, 2048);
  }

  // RoPE: Q gets 1/sqrt(HD) * log2(e) folded in (exp2-domain softmax)
  rope_apply_k<<<(4096 * NH_ * 64) / 256, 256, 0, stream>>>(bq, pos, tab, 4, 15, 0.12753102f);
  rope_apply_k<<<(4096 * NKV_ * 64) / 256, 256, 0, stream>>>(bk, pos, tab, 2, 3, 1.0f);

  // attention
  attn_fwd_k<<<dim3(512), 128, 0, stream>>>(bq, bk, VT, batt);

  // output projection (f32 out)
  if (big)
    gemm8_k<1><<<dim3(8, 32), 512, dynlds, stream>>>(batt, WoT, d_out, nullptr, nullptr, 4096, 2048, 2048);
  else
    gemm_bt_k<true, false><<<dim3(16, 32, 1), 256, 0, stream>>>(batt, WoT, WoT, d_out, d_out, 4096, 2048, 2048);
}

// Round 5
// 219.803 us; speedup vs baseline: 1.4102x; 1.4102x over previous
//
#include <hip/hip_runtime.h>
#include <hip/hip_bf16.h>
#include <stdint.h>
#include <math.h>

#define B_ 2
#define S_ 2048
#define H_ 2048
#define NH_ 16
#define NKV_ 4
#define HD_ 128

typedef __bf16 bf16;
typedef __bf16 bf16x8 __attribute__((ext_vector_type(8)));
typedef __bf16 bf16x4 __attribute__((ext_vector_type(4)));
typedef float f32x4 __attribute__((ext_vector_type(4)));

__device__ __forceinline__ void async_copy16(const void* g, void* l) {
  __builtin_amdgcn_global_load_lds(
      (const __attribute__((address_space(1))) void*)(uintptr_t)g,
      (__attribute__((address_space(3))) void*)(uintptr_t)l,
      16, 0, 0);
}

__device__ __forceinline__ f32x4 mfma16(bf16x8 a, bf16x8 b, f32x4 c) {
  return __builtin_amdgcn_mfma_f32_16x16x32_bf16(a, b, c, 0, 0, 0);
}

// ---------------- prep kernels ----------------

__global__ void f32_to_bf16_k(const float* __restrict__ in, bf16* __restrict__ o, int n) {
  int i = (blockIdx.x * 256 + threadIdx.x) * 4;
  if (i >= n) return;
  float4 v = *(const float4*)(in + i);
  bf16x4 r;
  r[0] = (bf16)v.x; r[1] = (bf16)v.y; r[2] = (bf16)v.z; r[3] = (bf16)v.w;
  *(bf16x4*)(o + i) = r;
}

// W: K x N f32 row-major  ->  Wt: N x K bf16 row-major
__global__ void transpose_to_bf16_k(const float* __restrict__ W, bf16* __restrict__ Wt,
                                    int K, int N) {
  __shared__ float tile[32][33];
  int n0 = blockIdx.x * 32, k0 = blockIdx.y * 32;
  int tx = threadIdx.x, ty = threadIdx.y;
#pragma unroll
  for (int j = 0; j < 32; j += 8)
    tile[ty + j][tx] = W[(size_t)(k0 + ty + j) * N + n0 + tx];
  __syncthreads();
#pragma unroll
  for (int j = 0; j < 32; j += 8)
    Wt[(size_t)(n0 + ty + j) * K + k0 + tx] = (bf16)tile[tx][ty + j];
}

__global__ void rope_table_k(float2* __restrict__ tab) {
  int i = blockIdx.x * 256 + threadIdx.x;  // S_*64
  int p = i >> 6, d = i & 63;
  float invf = expf(-((float)(2 * d) / 128.0f) * 9.210340371976184f);
  float fr = (float)p * invf;
  float sv, cv;
  sincosf(fr, &sv, &cv);
  tab[i] = make_float2(cv, sv);
}

__global__ void rope_apply_k(bf16* __restrict__ t, const int* __restrict__ pos_ids,
                             const float2* __restrict__ tab, int hshift, int hmask,
                             float scale) {
  int i = blockIdx.x * 256 + threadIdx.x;
  int d = i & 63;
  int tmp = i >> 6;
  int h = tmp & hmask;
  int row = tmp >> hshift;
  int pos = pos_ids[row];
  float2 cs = tab[pos * 64 + d];
  size_t base = (((size_t)row << hshift) + h) * HD_;
  float a = (float)t[base + d];
  float b = (float)t[base + d + 64];
  t[base + d]      = (bf16)((a * cs.x - b * cs.y) * scale);
  t[base + d + 64] = (bf16)((b * cs.x + a * cs.y) * scale);
}

// ---------------- 8-wave pipelined GEMM: C(MxN) = A(MxK) * Bt(NxK)^T ----------------
// BM=128, BN=256, BK=64; 8 waves (2M x 4N), 64x64 per wave. 3-stage LDS (144 KiB),
// counted vmcnt(6). Per K-tile: 2 phases of {8 ds_read | 3 stage | barrier | lgkm0 |
// 16 MFMA | barrier}. MODE: 0 = bf16 C0, 1 = f32 C0, 2 = QKV routing
// (cols <2048 -> C0=bq stride 2048; <2560 -> C1=bk stride 512; else C2=V^T).

template <int MODE>
__global__ __launch_bounds__(512) void gemm8_k(const bf16* __restrict__ A,
                                               const bf16* __restrict__ Bt,
                                               void* __restrict__ C0,
                                               void* __restrict__ C1,
                                               void* __restrict__ C2,
                                               int M, int N, int K) {
  extern __shared__ __align__(16) char smem[];
  const int tid = threadIdx.x;
  const int lane = tid & 63;
  const int w = tid >> 6;
  const int wm = w >> 2;          // 0..1
  const int wn = w & 3;           // 0..3
  const int g16 = lane >> 4, c16 = lane & 15;
  const int row0 = blockIdx.y * 128;
  const int col0 = blockIdx.x * 256;
  const int srow = tid >> 3;      // staging row within 64-row round
  const int sslot = tid & 7;
  const int ldsw = w * 1024;      // wave-uniform LDS dest piece (HW adds lane*16)

  auto stageA = [&](int s, int kt, int r) {
    int row = r * 64 + srow;
    int ss = sslot ^ (row & 7);
    async_copy16(A + (size_t)(row0 + row) * K + (kt << 6) + ss * 8,
                 smem + s * 49152 + r * 8192 + ldsw);
  };
  auto stageB = [&](int s, int kt, int r) {
    int row = r * 64 + srow;
    int ss = sslot ^ (row & 7);
    async_copy16(Bt + (size_t)(col0 + row) * K + (kt << 6) + ss * 8,
                 smem + s * 49152 + 16384 + r * 8192 + ldsw);
  };

  int offA[2][4], offB[2][4];
#pragma unroll
  for (int ks = 0; ks < 2; ++ks) {
#pragma unroll
    for (int i = 0; i < 4; ++i) {
      int ra = wm * 64 + i * 16 + c16;
      offA[ks][i] = ra * 128 + (((ks * 4 + g16) ^ (ra & 7)) << 4);
      int rb = wn * 64 + i * 16 + c16;
      offB[ks][i] = rb * 128 + (((ks * 4 + g16) ^ (rb & 7)) << 4);
    }
  }

  const f32x4 fz = {0.f, 0.f, 0.f, 0.f};
  f32x4 acc[4][4];
#pragma unroll
  for (int i = 0; i < 4; ++i)
#pragma unroll
    for (int j = 0; j < 4; ++j) acc[i][j] = fz;

  const int nkt = K >> 6;
  // prologue: stage tiles 0 and 1
#pragma unroll
  for (int r = 0; r < 2; ++r) stageA(0, 0, r);
#pragma unroll
  for (int r = 0; r < 4; ++r) stageB(0, 0, r);
#pragma unroll
  for (int r = 0; r < 2; ++r) stageA(1, 1, r);
#pragma unroll
  for (int r = 0; r < 4; ++r) stageB(1, 1, r);
  asm volatile("s_waitcnt vmcnt(6)" ::: "memory");
  __builtin_amdgcn_s_barrier();

  int ct = 0, pt = 2;
  for (int t = 0; t < nkt; ++t) {
    const char* Ab = smem + ct * 49152;
    const char* Bb = Ab + 16384;
    const bool pf = (t + 2 < nkt);
    const int kpf = t + 2;
    bf16x8 af[4], bfr[4];

    // ---- phase 1: ks=0, 16 MFMA ----
#pragma unroll
    for (int i = 0; i < 4; ++i) af[i] = *(const bf16x8*)(Ab + offA[0][i]);
#pragma unroll
    for (int j = 0; j < 4; ++j) bfr[j] = *(const bf16x8*)(Bb + offB[0][j]);
    if (pf) { stageA(pt, kpf, 0); stageA(pt, kpf, 1); stageB(pt, kpf, 0); }
    __builtin_amdgcn_s_barrier();
    asm volatile("s_waitcnt lgkmcnt(0)" ::: "memory");
    __builtin_amdgcn_sched_barrier(0);
    __builtin_amdgcn_s_setprio(1);
#pragma unroll
    for (int i = 0; i < 4; ++i)
#pragma unroll
      for (int j = 0; j < 4; ++j) acc[i][j] = mfma16(af[i], bfr[j], acc[i][j]);
    __builtin_amdgcn_s_setprio(0);
    __builtin_amdgcn_sched_barrier(0);
    __builtin_amdgcn_s_barrier();

    // ---- phase 2: ks=1, 16 MFMA; counted vmcnt for next tile ----
#pragma unroll
    for (int i = 0; i < 4; ++i) af[i] = *(const bf16x8*)(Ab + offA[1][i]);
#pragma unroll
    for (int j = 0; j < 4; ++j) bfr[j] = *(const bf16x8*)(Bb + offB[1][j]);
    if (pf) { stageB(pt, kpf, 1); stageB(pt, kpf, 2); stageB(pt, kpf, 3); }
    if (pf) asm volatile("s_waitcnt vmcnt(6)" ::: "memory");
    else    asm volatile("s_waitcnt vmcnt(0)" ::: "memory");
    __builtin_amdgcn_s_barrier();
    asm volatile("s_waitcnt lgkmcnt(0)" ::: "memory");
    __builtin_amdgcn_sched_barrier(0);
    __builtin_amdgcn_s_setprio(1);
#pragma unroll
    for (int i = 0; i < 4; ++i)
#pragma unroll
      for (int j = 0; j < 4; ++j) acc[i][j] = mfma16(af[i], bfr[j], acc[i][j]);
    __builtin_amdgcn_s_setprio(0);
    __builtin_amdgcn_sched_barrier(0);
    __builtin_amdgcn_s_barrier();

    ct = (ct == 2) ? 0 : ct + 1;
    pt = (pt == 2) ? 0 : pt + 1;
  }

  // C/D mapping: col = lane&15, row = (lane>>4)*4 + reg
#pragma unroll
  for (int i = 0; i < 4; ++i) {
    int gr0 = row0 + wm * 64 + i * 16 + g16 * 4;
#pragma unroll
    for (int j = 0; j < 4; ++j) {
      int gc = col0 + wn * 64 + j * 16 + c16;
      if constexpr (MODE == 2) {
        if (col0 < 2048) {
#pragma unroll
          for (int r = 0; r < 4; ++r)
            ((bf16*)C0)[(size_t)(gr0 + r) * 2048 + gc] = (bf16)acc[i][j][r];
        } else if (col0 < 2560) {
#pragma unroll
          for (int r = 0; r < 4; ++r)
            ((bf16*)C1)[(size_t)(gr0 + r) * 512 + (gc - 2048)] = (bf16)acc[i][j][r];
        } else {
          int dv = gc - 2560;                 // 0..511
          int hkv = dv >> 7, d = dv & 127;
          size_t va = (((size_t)(gr0 >> 11) * NKV_ + hkv) * HD_ + d) * S_ + (gr0 & 2047);
          bf16x4 pk;
#pragma unroll
          for (int r = 0; r < 4; ++r) pk[r] = (bf16)acc[i][j][r];
          *(bf16x4*)((bf16*)C2 + va) = pk;
        }
      } else {
#pragma unroll
        for (int r = 0; r < 4; ++r) {
          if constexpr (MODE == 1)
            ((float*)C0)[(size_t)(gr0 + r) * N + gc] = acc[i][j][r];
          else
            ((bf16*)C0)[(size_t)(gr0 + r) * N + gc] = (bf16)acc[i][j][r];
        }
      }
    }
  }
}

// ---------------- legacy 128^2 GEMM (fallback only) ----------------

template <bool OUT_F32, bool VT_Z1>
__global__ __launch_bounds__(256) void gemm_bt_k(const bf16* __restrict__ A,
                                                 const bf16* __restrict__ Bt0,
                                                 const bf16* __restrict__ Bt1,
                                                 void* __restrict__ C0, void* __restrict__ C1,
                                                 int M, int N, int K) {
  const bf16* __restrict__ Bt = (blockIdx.z == 0) ? Bt0 : Bt1;
  void* C = (blockIdx.z == 0) ? C0 : C1;
  __shared__ __align__(16) bf16 As[128 * 64];
  __shared__ __align__(16) bf16 Bs[128 * 64];
  const int tid = threadIdx.x;
  const int lane = tid & 63;
  const int w = tid >> 6;
  const int wm = w >> 1, wn = w & 1;
  const int g16 = lane >> 4, c16 = lane & 15;
  const int row0 = blockIdx.y * 128;
  const int col0 = blockIdx.x * 128;
  const int sr = lane >> 3;
  const int st = lane & 7;
  const int ss = st ^ sr;

  const f32x4 fz = {0.f, 0.f, 0.f, 0.f};
  f32x4 acc[4][4];
#pragma unroll
  for (int i = 0; i < 4; ++i)
#pragma unroll
    for (int j = 0; j < 4; ++j) acc[i][j] = fz;

  const int nkt = K >> 6;
  for (int kt = 0; kt < nkt; ++kt) {
    const int k0 = kt << 6;
    __syncthreads();
#pragma unroll
    for (int c = 0; c < 4; ++c) {
      int rbase = w * 32 + c * 8;
      async_copy16(A + (size_t)(row0 + rbase + sr) * K + k0 + ss * 8,
                   (char*)As + rbase * 128);
      async_copy16(Bt + (size_t)(col0 + rbase + sr) * K + k0 + ss * 8,
                   (char*)Bs + rbase * 128);
    }
    __syncthreads();
#pragma unroll
    for (int ks = 0; ks < 2; ++ks) {
      bf16x8 af[4], bfr[4];
#pragma unroll
      for (int t = 0; t < 4; ++t) {
        int ra = wm * 64 + t * 16 + c16;
        af[t] = *(const bf16x8*)((const char*)As + ra * 128 + (((ks * 4 + g16) ^ (ra & 7)) << 4));
        int rb = wn * 64 + t * 16 + c16;
        bfr[t] = *(const bf16x8*)((const char*)Bs + rb * 128 + (((ks * 4 + g16) ^ (rb & 7)) << 4));
      }
#pragma unroll
      for (int i = 0; i < 4; ++i)
#pragma unroll
        for (int j = 0; j < 4; ++j) acc[i][j] = mfma16(af[i], bfr[j], acc[i][j]);
    }
  }

  const bool vt = VT_Z1 && (blockIdx.z == 1);
#pragma unroll
  for (int i = 0; i < 4; ++i) {
    int gr0 = row0 + wm * 64 + i * 16 + g16 * 4;
#pragma unroll
    for (int j = 0; j < 4; ++j) {
      int gc = col0 + wn * 64 + j * 16 + c16;
      if (vt) {
        size_t va = ((size_t)((gr0 >> 11) * NKV_ + (gc >> 7)) * HD_ + (gc & 127)) * S_ + (gr0 & 2047);
        bf16x4 pk;
#pragma unroll
        for (int r = 0; r < 4; ++r) pk[r] = (bf16)acc[i][j][r];
        *(bf16x4*)((bf16*)C + va) = pk;
      } else {
#pragma unroll
        for (int r = 0; r < 4; ++r) {
          if constexpr (OUT_F32)
            ((float*)C)[(size_t)(gr0 + r) * N + gc] = acc[i][j][r];
          else
            ((bf16*)C)[(size_t)(gr0 + r) * N + gc] = (bf16)acc[i][j][r];
        }
      }
    }
  }
}

// ---------------- flash attention (causal, GQA) — round-3 structure ----------------
// QBLK=128 (4 waves x 32 q-rows), KVBLK=64, swapped QK^T with permuted K rows
// so P is fully in-lane for PV. exp2-domain softmax + defer-max + setprio(T5).
// VGPR budget: acc 64 + qf 32 + sc 32 (nq=2) — fits without spills (r4's nq=4 spilled).

__global__ __launch_bounds__(256, 2) void attn_fwd_k(const bf16* __restrict__ Qg,
                                                     const bf16* __restrict__ Kg,
                                                     const bf16* __restrict__ VTg,
                                                     bf16* __restrict__ Og) {
  __shared__ __align__(16) bf16 Ks[2][64 * 128];   // rows 256B (16 slots), swz slot^(row&7)
  __shared__ __align__(16) bf16 Vt[2][128 * 64];   // rows 128B (8 slots),  swz slot^(row&7)

  const int tid = threadIdx.x;
  const int lane = tid & 63;
  const int w = tid >> 6;
  const int g16 = lane >> 4;
  const int c16 = lane & 15;

  int bid = blockIdx.x;
  int rr_ = bid >> 5, bh = bid & 31;
  int qb = (rr_ < 8) ? (15 - rr_) : (rr_ - 8);
  const int b = bh >> 4;
  const int h = bh & 15;
  const int hkv = h >> 2;
  const int q0 = qb * 128;
  const int qw = q0 + w * 32;

  bf16x8 qf[2][4];
#pragma unroll
  for (int nq = 0; nq < 2; ++nq)
#pragma unroll
    for (int ksq = 0; ksq < 4; ++ksq)
      qf[nq][ksq] = *(const bf16x8*)(Qg + ((size_t)(b * S_ + qw + nq * 16 + c16) * NH_ + h) * HD_ + (ksq * 4 + g16) * 8);

  float m_run[2] = {-1e30f, -1e30f};
  float l_run[2] = {0.f, 0.f};
  const f32x4 fz = {0.f, 0.f, 0.f, 0.f};
  f32x4 acc[2][8];
#pragma unroll
  for (int nq = 0; nq < 2; ++nq)
#pragma unroll
    for (int dt = 0; dt < 8; ++dt) acc[nq][dt] = fz;

  const size_t kbase = ((size_t)b * S_ * NKV_ + hkv) * HD_;
  const size_t vbase = ((size_t)(b * NKV_ + hkv)) * HD_ * S_;

  auto stage = [&](int buf, int kv0) {
#pragma unroll
    for (int rd = 0; rd < 4; ++rd) {
      int Lb = rd * 256 + w * 64;
      int row = (Lb + lane) >> 4;
      int ssl = (lane & 15) ^ (row & 7);
      async_copy16(Kg + kbase + (size_t)(kv0 + row) * (NKV_ * HD_) + ssl * 8,
                   (char*)&Ks[buf][0] + Lb * 16);
    }
#pragma unroll
    for (int rd = 0; rd < 4; ++rd) {
      int Lb = rd * 256 + w * 64;
      int row = (Lb + lane) >> 3;
      int ssl = (lane & 7) ^ (row & 7);
      async_copy16(VTg + vbase + (size_t)row * S_ + kv0 + ssl * 8,
                   (char*)&Vt[buf][0] + Lb * 16);
    }
  };

  const int ntiles = 2 * qb + 2;
  stage(0, 0);
  int cur = 0;

  for (int t = 0; t < ntiles; ++t) {
    __syncthreads();
    if (t + 1 < ntiles) stage(cur ^ 1, (t + 1) * 64);
    const int kv0 = t * 64;

    if (kv0 <= qw + 31) {
      const bf16* KsC = &Ks[cur][0];
      const bf16* VtC = &Vt[cur][0];

      f32x4 sc[2][4];
#pragma unroll
      for (int nq = 0; nq < 2; ++nq)
#pragma unroll
        for (int mt = 0; mt < 4; ++mt) sc[nq][mt] = fz;

      __builtin_amdgcn_s_setprio(1);
#pragma unroll
      for (int ksq = 0; ksq < 4; ++ksq) {
        bf16x8 kf[4];
#pragma unroll
        for (int mt = 0; mt < 4; ++mt) {
          int gp = c16 >> 2, rp = c16 & 3;
          int blk = 8 * (mt >> 1) + 2 * gp + ((mt & 1) ^ (gp & 1));
          int row = blk * 4 + rp;
          kf[mt] = *(const bf16x8*)((const char*)KsC + row * 256 + (((ksq * 4 + g16) ^ (row & 7)) << 4));
        }
#pragma unroll
        for (int nq = 0; nq < 2; ++nq)
#pragma unroll
          for (int mt = 0; mt < 4; ++mt)
            sc[nq][mt] = mfma16(kf[mt], qf[nq][ksq], sc[nq][mt]);
      }
      __builtin_amdgcn_s_setprio(0);

      if (kv0 + 63 > qw) {
#pragma unroll
        for (int nq = 0; nq < 2; ++nq) {
          int qa = qw + nq * 16 + c16;
#pragma unroll
          for (int mt = 0; mt < 4; ++mt) {
            int blk = 8 * (mt >> 1) + 2 * g16 + ((mt & 1) ^ (g16 & 1));
#pragma unroll
            for (int r = 0; r < 4; ++r) {
              int ka = kv0 + blk * 4 + r;
              if (ka > qa) sc[nq][mt][r] = -1e30f;
            }
          }
        }
      }

      // ---- online softmax (base-2) with defer-max ----
      float mx[2];
#pragma unroll
      for (int nq = 0; nq < 2; ++nq) {
        float v = sc[nq][0][0];
#pragma unroll
        for (int mt = 0; mt < 4; ++mt)
#pragma unroll
          for (int r = 0; r < 4; ++r) v = fmaxf(v, sc[nq][mt][r]);
        v = fmaxf(v, __shfl_xor(v, 16));
        v = fmaxf(v, __shfl_xor(v, 32));
        mx[nq] = v;
      }
      if (__any((mx[0] > m_run[0] + 8.f) || (mx[1] > m_run[1] + 8.f))) {
#pragma unroll
        for (int nq = 0; nq < 2; ++nq) {
          float mn = fmaxf(m_run[nq], mx[nq]);
          float corr = exp2f(m_run[nq] - mn);
          m_run[nq] = mn;
          l_run[nq] *= corr;
#pragma unroll
          for (int dt = 0; dt < 8; ++dt) acc[nq][dt] *= corr;
        }
      }
#pragma unroll
      for (int nq = 0; nq < 2; ++nq) {
        float sum = 0.f;
#pragma unroll
        for (int mt = 0; mt < 4; ++mt)
#pragma unroll
          for (int r = 0; r < 4; ++r) {
            float p = exp2f(sc[nq][mt][r] - m_run[nq]);
            sc[nq][mt][r] = p;
            sum += p;
          }
        sum += __shfl_xor(sum, 16);
        sum += __shfl_xor(sum, 32);
        l_run[nq] += sum;
      }

      // ---- P -> bf16 fragments, in-lane ----
      bf16x8 pa[2][2];
#pragma unroll
      for (int nq = 0; nq < 2; ++nq)
#pragma unroll
        for (int ks = 0; ks < 2; ++ks) {
          f32x4 sA = (g16 & 1) ? sc[nq][2 * ks + 1] : sc[nq][2 * ks];
          f32x4 sB = (g16 & 1) ? sc[nq][2 * ks] : sc[nq][2 * ks + 1];
          bf16x8 tf;
          tf[0] = (bf16)sA[0]; tf[1] = (bf16)sA[1]; tf[2] = (bf16)sA[2]; tf[3] = (bf16)sA[3];
          tf[4] = (bf16)sB[0]; tf[5] = (bf16)sB[1]; tf[6] = (bf16)sB[2]; tf[7] = (bf16)sB[3];
          pa[nq][ks] = tf;
        }

      // ---- PV ----
      __builtin_amdgcn_s_setprio(1);
#pragma unroll
      for (int ks = 0; ks < 2; ++ks)
#pragma unroll
        for (int dt = 0; dt < 8; ++dt) {
          int rv = dt * 16 + c16;
          bf16x8 vf = *(const bf16x8*)((const char*)VtC + rv * 128 + (((ks * 4 + g16) ^ (rv & 7)) << 4));
          acc[0][dt] = mfma16(vf, pa[0][ks], acc[0][dt]);
          acc[1][dt] = mfma16(vf, pa[1][ks], acc[1][dt]);
        }
      __builtin_amdgcn_s_setprio(0);
    }
    cur ^= 1;
  }

#pragma unroll
  for (int nq = 0; nq < 2; ++nq) {
    float inv = 1.0f / l_run[nq];
    size_t base = ((size_t)(b * S_ + qw + nq * 16 + c16) * NH_ + h) * HD_ + g16 * 4;
#pragma unroll
    for (int dt = 0; dt < 8; ++dt) {
      bf16x4 ov;
#pragma unroll
      for (int r = 0; r < 4; ++r) ov[r] = (bf16)(acc[nq][dt][r] * inv);
      *(bf16x4*)(Og + base + dt * 16) = ov;
    }
  }
}

// ---------------- launcher ----------------

extern "C" void kernel_launch(void* const* d_in, const int* in_sizes, int n_in,
                              void* d_out, int out_size, void* d_ws, size_t ws_size,
                              hipStream_t stream) {
  const float* x  = (const float*)d_in[0];
  const int* pos  = (const int*)d_in[2];
  const float* Wq = (const float*)d_in[3];
  const float* Wk = (const float*)d_in[4];
  const float* Wv = (const float*)d_in[5];
  const float* Wo = (const float*)d_in[6];

  char* ws = (char*)d_ws;
  size_t off = 0;
  auto alloc = [&](size_t bytes) -> char* {
    char* p = ws + off;
    off += (bytes + 255) & ~(size_t)255;
    return p;
  };
  const size_t rows = (size_t)B_ * S_;
  bf16* xb    = (bf16*)alloc(rows * H_ * 2);
  bf16* bq    = (bf16*)alloc(rows * (NH_ * HD_) * 2);
  bf16* batt  = (bf16*)alloc(rows * (NH_ * HD_) * 2);
  bf16* WqkvT = (bf16*)alloc((size_t)3072 * H_ * 2);   // rows: Wq 0..2047 | Wk ..2559 | Wv ..3071
  bf16* WoT   = (bf16*)alloc((size_t)H_ * H_ * 2);
  bf16* bk    = (bf16*)alloc(rows * (NKV_ * HD_) * 2);
  bf16* VT    = (bf16*)alloc(rows * (NKV_ * HD_) * 2); // [b][hkv][d][S]
  float2* tab = (float2*)alloc((size_t)S_ * 64 * sizeof(float2));

  bf16* WqT = WqkvT;
  bf16* WkT = WqkvT + (size_t)2048 * H_;
  bf16* WvT = WqkvT + (size_t)2560 * H_;

  // enable 144 KiB dynamic LDS for the 8-wave GEMM (fallback to legacy if refused)
  auto* fqkv = gemm8_k<2>;
  auto* fo   = gemm8_k<1>;
  const int dynlds = 3 * 49152;
  bool big =
      (hipFuncSetAttribute((const void*)fqkv, hipFuncAttributeMaxDynamicSharedMemorySize, dynlds) == hipSuccess) &&
      (hipFuncSetAttribute((const void*)fo, hipFuncAttributeMaxDynamicSharedMemorySize, dynlds) == hipSuccess);

  // prep
  f32_to_bf16_k<<<(rows * H_) / (256 * 4), 256, 0, stream>>>(x, xb, rows * H_);
  transpose_to_bf16_k<<<dim3(H_ / 32, H_ / 32), dim3(32, 8), 0, stream>>>(Wq, WqT, H_, NH_ * HD_);
  transpose_to_bf16_k<<<dim3((NKV_ * HD_) / 32, H_ / 32), dim3(32, 8), 0, stream>>>(Wk, WkT, H_, NKV_ * HD_);
  transpose_to_bf16_k<<<dim3((NKV_ * HD_) / 32, H_ / 32), dim3(32, 8), 0, stream>>>(Wv, WvT, H_, NKV_ * HD_);
  transpose_to_bf16_k<<<dim3(H_ / 32, H_ / 32), dim3(32, 8), 0, stream>>>(Wo, WoT, H_, H_);
  rope_table_k<<<(S_ * 64) / 256, 256, 0, stream>>>(tab);

  // fused QKV projection (12 col-blocks: 8 Q, 2 K, 2 V^T)
  if (big) {
    gemm8_k<2><<<dim3(12, 32), 512, dynlds, stream>>>(xb, WqkvT, bq, bk, VT, 4096, 3072, 2048);
  } else {
    gemm_bt_k<false, false><<<dim3(16, 32, 1), 256, 0, stream>>>(xb, WqT, WqT, bq, bq, 4096, 2048, 2048);
    gemm_bt_k<false, true><<<dim3(4, 32, 2), 256, 0, stream>>>(xb, WkT, WvT, bk, VT, 4096, 512, 2048);
  }

  // RoPE: Q gets 1/sqrt(HD) * log2(e) folded in (exp2-domain softmax)
  rope_apply_k<<<(4096 * NH_ * 64) / 256, 256, 0, stream>>>(bq, pos, tab, 4, 15, 0.12753102f);
  rope_apply_k<<<(4096 * NKV_ * 64) / 256, 256, 0, stream>>>(bk, pos, tab, 2, 3, 1.0f);

  // attention
  attn_fwd_k<<<dim3(512), 256, 0, stream>>>(bq, bk, VT, batt);

  // output projection (f32 out)
  if (big)
    gemm8_k<1><<<dim3(8, 32), 512, dynlds, stream>>>(batt, WoT, d_out, nullptr, nullptr, 4096, 2048, 2048);
  else
    gemm_bt_k<true, false><<<dim3(16, 32, 1), 256, 0, stream>>>(batt, WoT, WoT, d_out, d_out, 4096, 2048, 2048);
}

// Round 6
// 212.454 us; speedup vs baseline: 1.4590x; 1.0346x over previous
//
#include <hip/hip_runtime.h>
#include <hip/hip_bf16.h>
#include <stdint.h>
#include <math.h>

#define B_ 2
#define S_ 2048
#define H_ 2048
#define NH_ 16
#define NKV_ 4
#define HD_ 128

typedef __bf16 bf16;
typedef __bf16 bf16x8 __attribute__((ext_vector_type(8)));
typedef __bf16 bf16x4 __attribute__((ext_vector_type(4)));
typedef float f32x4 __attribute__((ext_vector_type(4)));

__device__ __forceinline__ void async_copy16(const void* g, void* l) {
  __builtin_amdgcn_global_load_lds(
      (const __attribute__((address_space(1))) void*)(uintptr_t)g,
      (__attribute__((address_space(3))) void*)(uintptr_t)l,
      16, 0, 0);
}

__device__ __forceinline__ f32x4 mfma16(bf16x8 a, bf16x8 b, f32x4 c) {
  return __builtin_amdgcn_mfma_f32_16x16x32_bf16(a, b, c, 0, 0, 0);
}

// ---------------- prep kernels ----------------

__global__ void f32_to_bf16_k(const float* __restrict__ in, bf16* __restrict__ o, int n) {
  int i = (blockIdx.x * 256 + threadIdx.x) * 4;
  if (i >= n) return;
  float4 v = *(const float4*)(in + i);
  bf16x4 r;
  r[0] = (bf16)v.x; r[1] = (bf16)v.y; r[2] = (bf16)v.z; r[3] = (bf16)v.w;
  *(bf16x4*)(o + i) = r;
}

// W: K x N f32 row-major  ->  Wt: N x K bf16 row-major
__global__ void transpose_to_bf16_k(const float* __restrict__ W, bf16* __restrict__ Wt,
                                    int K, int N) {
  __shared__ float tile[32][33];
  int n0 = blockIdx.x * 32, k0 = blockIdx.y * 32;
  int tx = threadIdx.x, ty = threadIdx.y;
#pragma unroll
  for (int j = 0; j < 32; j += 8)
    tile[ty + j][tx] = W[(size_t)(k0 + ty + j) * N + n0 + tx];
  __syncthreads();
#pragma unroll
  for (int j = 0; j < 32; j += 8)
    Wt[(size_t)(n0 + ty + j) * K + k0 + tx] = (bf16)tile[tx][ty + j];
}

__global__ void rope_table_k(float2* __restrict__ tab) {
  int i = blockIdx.x * 256 + threadIdx.x;  // S_*64
  int p = i >> 6, d = i & 63;
  float invf = expf(-((float)(2 * d) / 128.0f) * 9.210340371976184f);
  float fr = (float)p * invf;
  float sv, cv;
  sincosf(fr, &sv, &cv);
  tab[i] = make_float2(cv, sv);
}

__global__ void rope_apply_k(bf16* __restrict__ t, const int* __restrict__ pos_ids,
                             const float2* __restrict__ tab, int hshift, int hmask,
                             float scale) {
  int i = blockIdx.x * 256 + threadIdx.x;
  int d = i & 63;
  int tmp = i >> 6;
  int h = tmp & hmask;
  int row = tmp >> hshift;
  int pos = pos_ids[row];
  float2 cs = tab[pos * 64 + d];
  size_t base = (((size_t)row << hshift) + h) * HD_;
  float a = (float)t[base + d];
  float b = (float)t[base + d + 64];
  t[base + d]      = (bf16)((a * cs.x - b * cs.y) * scale);
  t[base + d + 64] = (bf16)((b * cs.x + a * cs.y) * scale);
}

// ---------------- 256x256 8-wave GEMM (m201-style), QKV routing ----------------
// BM=BN=256, BK=64; 8 waves (2M x 4N), each 128x64 out (acc[8][4]). 2-buffer LDS
// (128 KiB dynamic). Per K-tile: 4 quadrant-phases x {ds_read A (+B cache ph0) |
// stage | barrier | lgkm0 | 16 MFMA | barrier}; all 8 staging rounds issued in
// phases 0-1; vmcnt(0) only at tile boundary (~2.5 phases after issue).
// MODE 2: cols <2048 -> C0=bq (stride 2048); <2560 -> C1=bk (512); else C2=V^T.

template <int MODE>
__global__ __launch_bounds__(512) void gemm256_k(const bf16* __restrict__ A,
                                                 const bf16* __restrict__ Bt,
                                                 void* __restrict__ C0,
                                                 void* __restrict__ C1,
                                                 void* __restrict__ C2,
                                                 int M, int N, int K) {
  extern __shared__ __align__(16) char smem[];
  const int tid = threadIdx.x;
  const int lane = tid & 63;
  const int w = tid >> 6;
  const int wm = w >> 2;          // 0..1 (M half)
  const int wn = w & 3;           // 0..3 (N quarter)
  const int g16 = lane >> 4, c16 = lane & 15;
  const int row0 = blockIdx.y * 256;
  const int col0 = blockIdx.x * 256;
  const int srow = tid >> 3;      // 0..63: row within 64-row staging round
  const int sslot = tid & 7;
  const int ldsw = w * 1024;      // wave-uniform LDS dest piece (HW adds lane*16)

  // staging round r in 0..7: r<4 -> A rows [r*64..), r>=4 -> B rows [(r-4)*64..)
  auto stage = [&](int buf, int kt, int r) {
    int row = (r & 3) * 64 + srow;
    int ss = sslot ^ (row & 7);
    const bf16* src = (r < 4) ? (A + (size_t)(row0 + row) * K)
                              : (Bt + (size_t)(col0 + row) * K);
    async_copy16(src + (kt << 6) + ss * 8,
                 smem + buf * 65536 + (r >> 2) * 32768 + (r & 3) * 8192 + ldsw);
  };

  int offA[2][8], offB[2][4];
#pragma unroll
  for (int ks = 0; ks < 2; ++ks) {
#pragma unroll
    for (int i = 0; i < 8; ++i) {
      int ra = wm * 128 + i * 16 + c16;
      offA[ks][i] = ra * 128 + (((ks * 4 + g16) ^ (ra & 7)) << 4);
    }
#pragma unroll
    for (int j = 0; j < 4; ++j) {
      int rb = wn * 64 + j * 16 + c16;
      offB[ks][j] = 32768 + rb * 128 + (((ks * 4 + g16) ^ (rb & 7)) << 4);
    }
  }

  const f32x4 fz = {0.f, 0.f, 0.f, 0.f};
  f32x4 acc[8][4];
#pragma unroll
  for (int i = 0; i < 8; ++i)
#pragma unroll
    for (int j = 0; j < 4; ++j) acc[i][j] = fz;

  const int nkt = K >> 6;
  // prologue: stage tile 0 into buf 0
#pragma unroll
  for (int r = 0; r < 8; ++r) stage(0, 0, r);
  asm volatile("s_waitcnt vmcnt(0)" ::: "memory");
  __builtin_amdgcn_s_barrier();

  for (int t = 0; t < nkt; ++t) {
    const char* Ab = smem + (t & 1) * 65536;
    const bool pf = (t + 1 < nkt);
    const int nb = (t + 1) & 1;
    bf16x8 bfr[2][4];   // B cache: lives across all 4 phases

    // ---- phase 0: quadrant m0,m1; read all B + A m01; stage rounds 0-3 ----
    {
      bf16x8 af[2][2];
#pragma unroll
      for (int ks = 0; ks < 2; ++ks) {
#pragma unroll
        for (int j = 0; j < 4; ++j) bfr[ks][j] = *(const bf16x8*)(Ab + offB[ks][j]);
        af[ks][0] = *(const bf16x8*)(Ab + offA[ks][0]);
        af[ks][1] = *(const bf16x8*)(Ab + offA[ks][1]);
      }
      if (pf) { stage(nb, t + 1, 0); stage(nb, t + 1, 1); stage(nb, t + 1, 2); stage(nb, t + 1, 3); }
      __builtin_amdgcn_s_barrier();
      asm volatile("s_waitcnt lgkmcnt(0)" ::: "memory");
      __builtin_amdgcn_sched_barrier(0);
      __builtin_amdgcn_s_setprio(1);
#pragma unroll
      for (int ks = 0; ks < 2; ++ks)
#pragma unroll
        for (int m = 0; m < 2; ++m)
#pragma unroll
          for (int j = 0; j < 4; ++j)
            acc[m][j] = mfma16(af[ks][m], bfr[ks][j], acc[m][j]);
      __builtin_amdgcn_s_setprio(0);
      __builtin_amdgcn_sched_barrier(0);
      __builtin_amdgcn_s_barrier();
    }

    // ---- phases 1-3: quadrants m23 / m45 / m67 ----
#pragma unroll
    for (int q = 1; q < 4; ++q) {
      bf16x8 af[2][2];
#pragma unroll
      for (int ks = 0; ks < 2; ++ks) {
        af[ks][0] = *(const bf16x8*)(Ab + offA[ks][q * 2]);
        af[ks][1] = *(const bf16x8*)(Ab + offA[ks][q * 2 + 1]);
      }
      if (q == 1 && pf) { stage(nb, t + 1, 4); stage(nb, t + 1, 5); stage(nb, t + 1, 6); stage(nb, t + 1, 7); }
      __builtin_amdgcn_s_barrier();
      asm volatile("s_waitcnt lgkmcnt(0)" ::: "memory");
      __builtin_amdgcn_sched_barrier(0);
      __builtin_amdgcn_s_setprio(1);
#pragma unroll
      for (int ks = 0; ks < 2; ++ks)
#pragma unroll
        for (int m = 0; m < 2; ++m)
#pragma unroll
          for (int j = 0; j < 4; ++j)
            acc[q * 2 + m][j] = mfma16(af[ks][m], bfr[ks][j], acc[q * 2 + m][j]);
      __builtin_amdgcn_s_setprio(0);
      __builtin_amdgcn_sched_barrier(0);
      if (q == 3 && pf) asm volatile("s_waitcnt vmcnt(0)" ::: "memory");
      __builtin_amdgcn_s_barrier();
    }
  }

  // C/D mapping: col = lane&15, row = (lane>>4)*4 + reg
#pragma unroll
  for (int i = 0; i < 8; ++i) {
    int gr0 = row0 + wm * 128 + i * 16 + g16 * 4;
#pragma unroll
    for (int j = 0; j < 4; ++j) {
      int gc = col0 + wn * 64 + j * 16 + c16;
      if constexpr (MODE == 2) {
        if (col0 < 2048) {
#pragma unroll
          for (int r = 0; r < 4; ++r)
            ((bf16*)C0)[(size_t)(gr0 + r) * 2048 + gc] = (bf16)acc[i][j][r];
        } else if (col0 < 2560) {
#pragma unroll
          for (int r = 0; r < 4; ++r)
            ((bf16*)C1)[(size_t)(gr0 + r) * 512 + (gc - 2048)] = (bf16)acc[i][j][r];
        } else {
          int dv = gc - 2560;                 // 0..511
          int hkv = dv >> 7, d = dv & 127;
          size_t va = (((size_t)(gr0 >> 11) * NKV_ + hkv) * HD_ + d) * S_ + (gr0 & 2047);
          bf16x4 pk;
#pragma unroll
          for (int r = 0; r < 4; ++r) pk[r] = (bf16)acc[i][j][r];
          *(bf16x4*)((bf16*)C2 + va) = pk;
        }
      } else {
#pragma unroll
        for (int r = 0; r < 4; ++r) {
          if constexpr (MODE == 1)
            ((float*)C0)[(size_t)(gr0 + r) * N + gc] = acc[i][j][r];
          else
            ((bf16*)C0)[(size_t)(gr0 + r) * N + gc] = (bf16)acc[i][j][r];
        }
      }
    }
  }
}

// ---------------- 128x256 8-wave pipelined GEMM (O-proj: 256 blocks exact) ----------------

template <int MODE>
__global__ __launch_bounds__(512) void gemm8_k(const bf16* __restrict__ A,
                                               const bf16* __restrict__ Bt,
                                               void* __restrict__ C0,
                                               void* __restrict__ C1,
                                               void* __restrict__ C2,
                                               int M, int N, int K) {
  extern __shared__ __align__(16) char smem[];
  const int tid = threadIdx.x;
  const int lane = tid & 63;
  const int w = tid >> 6;
  const int wm = w >> 2;          // 0..1
  const int wn = w & 3;           // 0..3
  const int g16 = lane >> 4, c16 = lane & 15;
  const int row0 = blockIdx.y * 128;
  const int col0 = blockIdx.x * 256;
  const int srow = tid >> 3;
  const int sslot = tid & 7;
  const int ldsw = w * 1024;

  auto stageA = [&](int s, int kt, int r) {
    int row = r * 64 + srow;
    int ss = sslot ^ (row & 7);
    async_copy16(A + (size_t)(row0 + row) * K + (kt << 6) + ss * 8,
                 smem + s * 49152 + r * 8192 + ldsw);
  };
  auto stageB = [&](int s, int kt, int r) {
    int row = r * 64 + srow;
    int ss = sslot ^ (row & 7);
    async_copy16(Bt + (size_t)(col0 + row) * K + (kt << 6) + ss * 8,
                 smem + s * 49152 + 16384 + r * 8192 + ldsw);
  };

  int offA[2][4], offB[2][4];
#pragma unroll
  for (int ks = 0; ks < 2; ++ks) {
#pragma unroll
    for (int i = 0; i < 4; ++i) {
      int ra = wm * 64 + i * 16 + c16;
      offA[ks][i] = ra * 128 + (((ks * 4 + g16) ^ (ra & 7)) << 4);
      int rb = wn * 64 + i * 16 + c16;
      offB[ks][i] = rb * 128 + (((ks * 4 + g16) ^ (rb & 7)) << 4);
    }
  }

  const f32x4 fz = {0.f, 0.f, 0.f, 0.f};
  f32x4 acc[4][4];
#pragma unroll
  for (int i = 0; i < 4; ++i)
#pragma unroll
    for (int j = 0; j < 4; ++j) acc[i][j] = fz;

  const int nkt = K >> 6;
#pragma unroll
  for (int r = 0; r < 2; ++r) stageA(0, 0, r);
#pragma unroll
  for (int r = 0; r < 4; ++r) stageB(0, 0, r);
#pragma unroll
  for (int r = 0; r < 2; ++r) stageA(1, 1, r);
#pragma unroll
  for (int r = 0; r < 4; ++r) stageB(1, 1, r);
  asm volatile("s_waitcnt vmcnt(6)" ::: "memory");
  __builtin_amdgcn_s_barrier();

  int ct = 0, pt = 2;
  for (int t = 0; t < nkt; ++t) {
    const char* Ab = smem + ct * 49152;
    const char* Bb = Ab + 16384;
    const bool pf = (t + 2 < nkt);
    const int kpf = t + 2;
    bf16x8 af[4], bfr[4];

#pragma unroll
    for (int i = 0; i < 4; ++i) af[i] = *(const bf16x8*)(Ab + offA[0][i]);
#pragma unroll
    for (int j = 0; j < 4; ++j) bfr[j] = *(const bf16x8*)(Bb + offB[0][j]);
    if (pf) { stageA(pt, kpf, 0); stageA(pt, kpf, 1); stageB(pt, kpf, 0); }
    __builtin_amdgcn_s_barrier();
    asm volatile("s_waitcnt lgkmcnt(0)" ::: "memory");
    __builtin_amdgcn_sched_barrier(0);
    __builtin_amdgcn_s_setprio(1);
#pragma unroll
    for (int i = 0; i < 4; ++i)
#pragma unroll
      for (int j = 0; j < 4; ++j) acc[i][j] = mfma16(af[i], bfr[j], acc[i][j]);
    __builtin_amdgcn_s_setprio(0);
    __builtin_amdgcn_sched_barrier(0);
    __builtin_amdgcn_s_barrier();

#pragma unroll
    for (int i = 0; i < 4; ++i) af[i] = *(const bf16x8*)(Ab + offA[1][i]);
#pragma unroll
    for (int j = 0; j < 4; ++j) bfr[j] = *(const bf16x8*)(Bb + offB[1][j]);
    if (pf) { stageB(pt, kpf, 1); stageB(pt, kpf, 2); stageB(pt, kpf, 3); }
    if (pf) asm volatile("s_waitcnt vmcnt(6)" ::: "memory");
    else    asm volatile("s_waitcnt vmcnt(0)" ::: "memory");
    __builtin_amdgcn_s_barrier();
    asm volatile("s_waitcnt lgkmcnt(0)" ::: "memory");
    __builtin_amdgcn_sched_barrier(0);
    __builtin_amdgcn_s_setprio(1);
#pragma unroll
    for (int i = 0; i < 4; ++i)
#pragma unroll
      for (int j = 0; j < 4; ++j) acc[i][j] = mfma16(af[i], bfr[j], acc[i][j]);
    __builtin_amdgcn_s_setprio(0);
    __builtin_amdgcn_sched_barrier(0);
    __builtin_amdgcn_s_barrier();

    ct = (ct == 2) ? 0 : ct + 1;
    pt = (pt == 2) ? 0 : pt + 1;
  }

#pragma unroll
  for (int i = 0; i < 4; ++i) {
    int gr0 = row0 + wm * 64 + i * 16 + g16 * 4;
#pragma unroll
    for (int j = 0; j < 4; ++j) {
      int gc = col0 + wn * 64 + j * 16 + c16;
#pragma unroll
      for (int r = 0; r < 4; ++r) {
        if constexpr (MODE == 1)
          ((float*)C0)[(size_t)(gr0 + r) * N + gc] = acc[i][j][r];
        else
          ((bf16*)C0)[(size_t)(gr0 + r) * N + gc] = (bf16)acc[i][j][r];
      }
    }
  }
}

// ---------------- legacy 128^2 GEMM (fallback only) ----------------

template <bool OUT_F32, bool VT_Z1>
__global__ __launch_bounds__(256) void gemm_bt_k(const bf16* __restrict__ A,
                                                 const bf16* __restrict__ Bt0,
                                                 const bf16* __restrict__ Bt1,
                                                 void* __restrict__ C0, void* __restrict__ C1,
                                                 int M, int N, int K) {
  const bf16* __restrict__ Bt = (blockIdx.z == 0) ? Bt0 : Bt1;
  void* C = (blockIdx.z == 0) ? C0 : C1;
  __shared__ __align__(16) bf16 As[128 * 64];
  __shared__ __align__(16) bf16 Bs[128 * 64];
  const int tid = threadIdx.x;
  const int lane = tid & 63;
  const int w = tid >> 6;
  const int wm = w >> 1, wn = w & 1;
  const int g16 = lane >> 4, c16 = lane & 15;
  const int row0 = blockIdx.y * 128;
  const int col0 = blockIdx.x * 128;
  const int sr = lane >> 3;
  const int st = lane & 7;
  const int ss = st ^ sr;

  const f32x4 fz = {0.f, 0.f, 0.f, 0.f};
  f32x4 acc[4][4];
#pragma unroll
  for (int i = 0; i < 4; ++i)
#pragma unroll
    for (int j = 0; j < 4; ++j) acc[i][j] = fz;

  const int nkt = K >> 6;
  for (int kt = 0; kt < nkt; ++kt) {
    const int k0 = kt << 6;
    __syncthreads();
#pragma unroll
    for (int c = 0; c < 4; ++c) {
      int rbase = w * 32 + c * 8;
      async_copy16(A + (size_t)(row0 + rbase + sr) * K + k0 + ss * 8,
                   (char*)As + rbase * 128);
      async_copy16(Bt + (size_t)(col0 + rbase + sr) * K + k0 + ss * 8,
                   (char*)Bs + rbase * 128);
    }
    __syncthreads();
#pragma unroll
    for (int ks = 0; ks < 2; ++ks) {
      bf16x8 af[4], bfr[4];
#pragma unroll
      for (int t = 0; t < 4; ++t) {
        int ra = wm * 64 + t * 16 + c16;
        af[t] = *(const bf16x8*)((const char*)As + ra * 128 + (((ks * 4 + g16) ^ (ra & 7)) << 4));
        int rb = wn * 64 + t * 16 + c16;
        bfr[t] = *(const bf16x8*)((const char*)Bs + rb * 128 + (((ks * 4 + g16) ^ (rb & 7)) << 4));
      }
#pragma unroll
      for (int i = 0; i < 4; ++i)
#pragma unroll
        for (int j = 0; j < 4; ++j) acc[i][j] = mfma16(af[i], bfr[j], acc[i][j]);
    }
  }

  const bool vt = VT_Z1 && (blockIdx.z == 1);
#pragma unroll
  for (int i = 0; i < 4; ++i) {
    int gr0 = row0 + wm * 64 + i * 16 + g16 * 4;
#pragma unroll
    for (int j = 0; j < 4; ++j) {
      int gc = col0 + wn * 64 + j * 16 + c16;
      if (vt) {
        size_t va = ((size_t)((gr0 >> 11) * NKV_ + (gc >> 7)) * HD_ + (gc & 127)) * S_ + (gr0 & 2047);
        bf16x4 pk;
#pragma unroll
        for (int r = 0; r < 4; ++r) pk[r] = (bf16)acc[i][j][r];
        *(bf16x4*)((bf16*)C + va) = pk;
      } else {
#pragma unroll
        for (int r = 0; r < 4; ++r) {
          if constexpr (OUT_F32)
            ((float*)C)[(size_t)(gr0 + r) * N + gc] = acc[i][j][r];
          else
            ((bf16*)C)[(size_t)(gr0 + r) * N + gc] = (bf16)acc[i][j][r];
        }
      }
    }
  }
}

// ---------------- flash attention (causal, GQA) — r3/r5 structure ----------------

__global__ __launch_bounds__(256, 2) void attn_fwd_k(const bf16* __restrict__ Qg,
                                                     const bf16* __restrict__ Kg,
                                                     const bf16* __restrict__ VTg,
                                                     bf16* __restrict__ Og) {
  __shared__ __align__(16) bf16 Ks[2][64 * 128];
  __shared__ __align__(16) bf16 Vt[2][128 * 64];

  const int tid = threadIdx.x;
  const int lane = tid & 63;
  const int w = tid >> 6;
  const int g16 = lane >> 4;
  const int c16 = lane & 15;

  int bid = blockIdx.x;
  int rr_ = bid >> 5, bh = bid & 31;
  int qb = (rr_ < 8) ? (15 - rr_) : (rr_ - 8);
  const int b = bh >> 4;
  const int h = bh & 15;
  const int hkv = h >> 2;
  const int q0 = qb * 128;
  const int qw = q0 + w * 32;

  bf16x8 qf[2][4];
#pragma unroll
  for (int nq = 0; nq < 2; ++nq)
#pragma unroll
    for (int ksq = 0; ksq < 4; ++ksq)
      qf[nq][ksq] = *(const bf16x8*)(Qg + ((size_t)(b * S_ + qw + nq * 16 + c16) * NH_ + h) * HD_ + (ksq * 4 + g16) * 8);

  float m_run[2] = {-1e30f, -1e30f};
  float l_run[2] = {0.f, 0.f};
  const f32x4 fz = {0.f, 0.f, 0.f, 0.f};
  f32x4 acc[2][8];
#pragma unroll
  for (int nq = 0; nq < 2; ++nq)
#pragma unroll
    for (int dt = 0; dt < 8; ++dt) acc[nq][dt] = fz;

  const size_t kbase = ((size_t)b * S_ * NKV_ + hkv) * HD_;
  const size_t vbase = ((size_t)(b * NKV_ + hkv)) * HD_ * S_;

  auto stage = [&](int buf, int kv0) {
#pragma unroll
    for (int rd = 0; rd < 4; ++rd) {
      int Lb = rd * 256 + w * 64;
      int row = (Lb + lane) >> 4;
      int ssl = (lane & 15) ^ (row & 7);
      async_copy16(Kg + kbase + (size_t)(kv0 + row) * (NKV_ * HD_) + ssl * 8,
                   (char*)&Ks[buf][0] + Lb * 16);
    }
#pragma unroll
    for (int rd = 0; rd < 4; ++rd) {
      int Lb = rd * 256 + w * 64;
      int row = (Lb + lane) >> 3;
      int ssl = (lane & 7) ^ (row & 7);
      async_copy16(VTg + vbase + (size_t)row * S_ + kv0 + ssl * 8,
                   (char*)&Vt[buf][0] + Lb * 16);
    }
  };

  const int ntiles = 2 * qb + 2;
  stage(0, 0);
  int cur = 0;

  for (int t = 0; t < ntiles; ++t) {
    __syncthreads();
    if (t + 1 < ntiles) stage(cur ^ 1, (t + 1) * 64);
    const int kv0 = t * 64;

    if (kv0 <= qw + 31) {
      const bf16* KsC = &Ks[cur][0];
      const bf16* VtC = &Vt[cur][0];

      f32x4 sc[2][4];
#pragma unroll
      for (int nq = 0; nq < 2; ++nq)
#pragma unroll
        for (int mt = 0; mt < 4; ++mt) sc[nq][mt] = fz;

      __builtin_amdgcn_s_setprio(1);
#pragma unroll
      for (int ksq = 0; ksq < 4; ++ksq) {
        bf16x8 kf[4];
#pragma unroll
        for (int mt = 0; mt < 4; ++mt) {
          int gp = c16 >> 2, rp = c16 & 3;
          int blk = 8 * (mt >> 1) + 2 * gp + ((mt & 1) ^ (gp & 1));
          int row = blk * 4 + rp;
          kf[mt] = *(const bf16x8*)((const char*)KsC + row * 256 + (((ksq * 4 + g16) ^ (row & 7)) << 4));
        }
#pragma unroll
        for (int nq = 0; nq < 2; ++nq)
#pragma unroll
          for (int mt = 0; mt < 4; ++mt)
            sc[nq][mt] = mfma16(kf[mt], qf[nq][ksq], sc[nq][mt]);
      }
      __builtin_amdgcn_s_setprio(0);

      if (kv0 + 63 > qw) {
#pragma unroll
        for (int nq = 0; nq < 2; ++nq) {
          int qa = qw + nq * 16 + c16;
#pragma unroll
          for (int mt = 0; mt < 4; ++mt) {
            int blk = 8 * (mt >> 1) + 2 * g16 + ((mt & 1) ^ (g16 & 1));
#pragma unroll
            for (int r = 0; r < 4; ++r) {
              int ka = kv0 + blk * 4 + r;
              if (ka > qa) sc[nq][mt][r] = -1e30f;
            }
          }
        }
      }

      float mx[2];
#pragma unroll
      for (int nq = 0; nq < 2; ++nq) {
        float v = sc[nq][0][0];
#pragma unroll
        for (int mt = 0; mt < 4; ++mt)
#pragma unroll
          for (int r = 0; r < 4; ++r) v = fmaxf(v, sc[nq][mt][r]);
        v = fmaxf(v, __shfl_xor(v, 16));
        v = fmaxf(v, __shfl_xor(v, 32));
        mx[nq] = v;
      }
      if (__any((mx[0] > m_run[0] + 8.f) || (mx[1] > m_run[1] + 8.f))) {
#pragma unroll
        for (int nq = 0; nq < 2; ++nq) {
          float mn = fmaxf(m_run[nq], mx[nq]);
          float corr = exp2f(m_run[nq] - mn);
          m_run[nq] = mn;
          l_run[nq] *= corr;
#pragma unroll
          for (int dt = 0; dt < 8; ++dt) acc[nq][dt] *= corr;
        }
      }
#pragma unroll
      for (int nq = 0; nq < 2; ++nq) {
        float sum = 0.f;
#pragma unroll
        for (int mt = 0; mt < 4; ++mt)
#pragma unroll
          for (int r = 0; r < 4; ++r) {
            float p = exp2f(sc[nq][mt][r] - m_run[nq]);
            sc[nq][mt][r] = p;
            sum += p;
          }
        sum += __shfl_xor(sum, 16);
        sum += __shfl_xor(sum, 32);
        l_run[nq] += sum;
      }

      bf16x8 pa[2][2];
#pragma unroll
      for (int nq = 0; nq < 2; ++nq)
#pragma unroll
        for (int ks = 0; ks < 2; ++ks) {
          f32x4 sA = (g16 & 1) ? sc[nq][2 * ks + 1] : sc[nq][2 * ks];
          f32x4 sB = (g16 & 1) ? sc[nq][2 * ks] : sc[nq][2 * ks + 1];
          bf16x8 tf;
          tf[0] = (bf16)sA[0]; tf[1] = (bf16)sA[1]; tf[2] = (bf16)sA[2]; tf[3] = (bf16)sA[3];
          tf[4] = (bf16)sB[0]; tf[5] = (bf16)sB[1]; tf[6] = (bf16)sB[2]; tf[7] = (bf16)sB[3];
          pa[nq][ks] = tf;
        }

      __builtin_amdgcn_s_setprio(1);
#pragma unroll
      for (int ks = 0; ks < 2; ++ks)
#pragma unroll
        for (int dt = 0; dt < 8; ++dt) {
          int rv = dt * 16 + c16;
          bf16x8 vf = *(const bf16x8*)((const char*)VtC + rv * 128 + (((ks * 4 + g16) ^ (rv & 7)) << 4));
          acc[0][dt] = mfma16(vf, pa[0][ks], acc[0][dt]);
          acc[1][dt] = mfma16(vf, pa[1][ks], acc[1][dt]);
        }
      __builtin_amdgcn_s_setprio(0);
    }
    cur ^= 1;
  }

#pragma unroll
  for (int nq = 0; nq < 2; ++nq) {
    float inv = 1.0f / l_run[nq];
    size_t base = ((size_t)(b * S_ + qw + nq * 16 + c16) * NH_ + h) * HD_ + g16 * 4;
#pragma unroll
    for (int dt = 0; dt < 8; ++dt) {
      bf16x4 ov;
#pragma unroll
      for (int r = 0; r < 4; ++r) ov[r] = (bf16)(acc[nq][dt][r] * inv);
      *(bf16x4*)(Og + base + dt * 16) = ov;
    }
  }
}

// ---------------- launcher ----------------

extern "C" void kernel_launch(void* const* d_in, const int* in_sizes, int n_in,
                              void* d_out, int out_size, void* d_ws, size_t ws_size,
                              hipStream_t stream) {
  const float* x  = (const float*)d_in[0];
  const int* pos  = (const int*)d_in[2];
  const float* Wq = (const float*)d_in[3];
  const float* Wk = (const float*)d_in[4];
  const float* Wv = (const float*)d_in[5];
  const float* Wo = (const float*)d_in[6];

  char* ws = (char*)d_ws;
  size_t off = 0;
  auto alloc = [&](size_t bytes) -> char* {
    char* p = ws + off;
    off += (bytes + 255) & ~(size_t)255;
    return p;
  };
  const size_t rows = (size_t)B_ * S_;
  bf16* xb    = (bf16*)alloc(rows * H_ * 2);
  bf16* bq    = (bf16*)alloc(rows * (NH_ * HD_) * 2);
  bf16* batt  = (bf16*)alloc(rows * (NH_ * HD_) * 2);
  bf16* WqkvT = (bf16*)alloc((size_t)3072 * H_ * 2);   // rows: Wq 0..2047 | Wk ..2559 | Wv ..3071
  bf16* WoT   = (bf16*)alloc((size_t)H_ * H_ * 2);
  bf16* bk    = (bf16*)alloc(rows * (NKV_ * HD_) * 2);
  bf16* VT    = (bf16*)alloc(rows * (NKV_ * HD_) * 2); // [b][hkv][d][S]
  float2* tab = (float2*)alloc((size_t)S_ * 64 * sizeof(float2));

  bf16* WqT = WqkvT;
  bf16* WkT = WqkvT + (size_t)2048 * H_;
  bf16* WvT = WqkvT + (size_t)2560 * H_;

  auto* fqkv = gemm256_k<2>;
  auto* fo   = gemm8_k<1>;
  const int lds256 = 2 * 65536;   // 128 KiB
  const int lds8   = 3 * 49152;   // 144 KiB
  bool big =
      (hipFuncSetAttribute((const void*)fqkv, hipFuncAttributeMaxDynamicSharedMemorySize, lds256) == hipSuccess) &&
      (hipFuncSetAttribute((const void*)fo, hipFuncAttributeMaxDynamicSharedMemorySize, lds8) == hipSuccess);

  // prep
  f32_to_bf16_k<<<(rows * H_) / (256 * 4), 256, 0, stream>>>(x, xb, rows * H_);
  transpose_to_bf16_k<<<dim3(H_ / 32, H_ / 32), dim3(32, 8), 0, stream>>>(Wq, WqT, H_, NH_ * HD_);
  transpose_to_bf16_k<<<dim3((NKV_ * HD_) / 32, H_ / 32), dim3(32, 8), 0, stream>>>(Wk, WkT, H_, NKV_ * HD_);
  transpose_to_bf16_k<<<dim3((NKV_ * HD_) / 32, H_ / 32), dim3(32, 8), 0, stream>>>(Wv, WvT, H_, NKV_ * HD_);
  transpose_to_bf16_k<<<dim3(H_ / 32, H_ / 32), dim3(32, 8), 0, stream>>>(Wo, WoT, H_, H_);
  rope_table_k<<<(S_ * 64) / 256, 256, 0, stream>>>(tab);

  // fused QKV projection: 256^2 tile, 12 x-blocks (8 Q, 2 K, 2 V^T), single round
  if (big) {
    gemm256_k<2><<<dim3(12, 16), 512, lds256, stream>>>(xb, WqkvT, bq, bk, VT, 4096, 3072, 2048);
  } else {
    gemm_bt_k<false, false><<<dim3(16, 32, 1), 256, 0, stream>>>(xb, WqT, WqT, bq, bq, 4096, 2048, 2048);
    gemm_bt_k<false, true><<<dim3(4, 32, 2), 256, 0, stream>>>(xb, WkT, WvT, bk, VT, 4096, 512, 2048);
  }

  // RoPE: Q gets 1/sqrt(HD) * log2(e) folded in (exp2-domain softmax)
  rope_apply_k<<<(4096 * NH_ * 64) / 256, 256, 0, stream>>>(bq, pos, tab, 4, 15, 0.12753102f);
  rope_apply_k<<<(4096 * NKV_ * 64) / 256, 256, 0, stream>>>(bk, pos, tab, 2, 3, 1.0f);

  // attention
  attn_fwd_k<<<dim3(512), 256, 0, stream>>>(bq, bk, VT, batt);

  // output projection (f32 out): 128x256 tile, 8x32 = 256 blocks exact fit
  if (big)
    gemm8_k<1><<<dim3(8, 32), 512, lds8, stream>>>(batt, WoT, d_out, nullptr, nullptr, 4096, 2048, 2048);
  else
    gemm_bt_k<true, false><<<dim3(16, 32, 1), 256, 0, stream>>>(batt, WoT, WoT, d_out, d_out, 4096, 2048, 2048);
}

// Round 7
// 199.153 us; speedup vs baseline: 1.5564x; 1.0668x over previous
//
#include <hip/hip_runtime.h>
#include <hip/hip_bf16.h>
#include <stdint.h>
#include <math.h>

#define B_ 2
#define S_ 2048
#define H_ 2048
#define NH_ 16
#define NKV_ 4
#define HD_ 128

typedef __bf16 bf16;
typedef __bf16 bf16x8 __attribute__((ext_vector_type(8)));
typedef __bf16 bf16x4 __attribute__((ext_vector_type(4)));
typedef float f32x4 __attribute__((ext_vector_type(4)));

__device__ __forceinline__ void async_copy16(const void* g, void* l) {
  __builtin_amdgcn_global_load_lds(
      (const __attribute__((address_space(1))) void*)(uintptr_t)g,
      (__attribute__((address_space(3))) void*)(uintptr_t)l,
      16, 0, 0);
}

__device__ __forceinline__ f32x4 mfma16(bf16x8 a, bf16x8 b, f32x4 c) {
  return __builtin_amdgcn_mfma_f32_16x16x32_bf16(a, b, c, 0, 0, 0);
}

// ---------------- prep kernels ----------------

__global__ void f32_to_bf16_k(const float* __restrict__ in, bf16* __restrict__ o, int n) {
  int i = (blockIdx.x * 256 + threadIdx.x) * 4;
  if (i >= n) return;
  float4 v = *(const float4*)(in + i);
  bf16x4 r;
  r[0] = (bf16)v.x; r[1] = (bf16)v.y; r[2] = (bf16)v.z; r[3] = (bf16)v.w;
  *(bf16x4*)(o + i) = r;
}

// merged transpose: Wq|Wk|Wv -> WqkvT rows {0,2048,2560}, Wo -> WoT. All K=2048.
__global__ void transpose_all_k(const float* __restrict__ Wq, const float* __restrict__ Wk,
                                const float* __restrict__ Wv, const float* __restrict__ Wo,
                                bf16* __restrict__ WqkvT, bf16* __restrict__ WoT) {
  __shared__ float tile[32][33];
  int bid = blockIdx.x;
  const float* W; bf16* Wt; int N, bx, by;
  if (bid < 4096)      { W = Wq; Wt = WqkvT;                          N = 2048; int b2 = bid;        bx = b2 & 63; by = b2 >> 6; }
  else if (bid < 5120) { W = Wk; Wt = WqkvT + (size_t)2048 * 2048;    N = 512;  int b2 = bid - 4096; bx = b2 & 15; by = b2 >> 4; }
  else if (bid < 6144) { W = Wv; Wt = WqkvT + (size_t)2560 * 2048;    N = 512;  int b2 = bid - 5120; bx = b2 & 15; by = b2 >> 4; }
  else                 { W = Wo; Wt = WoT;                            N = 2048; int b2 = bid - 6144; bx = b2 & 63; by = b2 >> 6; }
  const int K = 2048;
  int n0 = bx * 32, k0 = by * 32;
  int tx = threadIdx.x, ty = threadIdx.y;
#pragma unroll
  for (int j = 0; j < 32; j += 8)
    tile[ty + j][tx] = W[(size_t)(k0 + ty + j) * N + n0 + tx];
  __syncthreads();
#pragma unroll
  for (int j = 0; j < 32; j += 8)
    Wt[(size_t)(n0 + ty + j) * K + k0 + tx] = (bf16)tile[tx][ty + j];
}

__global__ void rope_table_k(float2* __restrict__ tab) {
  int i = blockIdx.x * 256 + threadIdx.x;  // S_*64
  int p = i >> 6, d = i & 63;
  float invf = expf(-((float)(2 * d) / 128.0f) * 9.210340371976184f);
  float fr = (float)p * invf;
  float sv, cv;
  sincosf(fr, &sv, &cv);
  tab[i] = make_float2(cv, sv);
}

// vectorized RoPE: each thread handles 8 (d, d+64) pairs via bf16x8 loads (G13).
__global__ void rope_apply_v8_k(bf16* __restrict__ t, const int* __restrict__ pos_ids,
                                const float2* __restrict__ tab, int hshift, int hmask,
                                float scale) {
  int i = blockIdx.x * 256 + threadIdx.x;   // rows*heads*8
  int g = i & 7;                             // 8-wide chunk of d in [0,64)
  int tmp = i >> 3;
  int h = tmp & hmask;
  int row = tmp >> hshift;
  int pos = pos_ids[row];
  size_t base = (((size_t)row << hshift) + h) * HD_ + g * 8;
  const float2* tb = tab + pos * 64 + g * 8;
  bf16x8 lo = *(const bf16x8*)(t + base);
  bf16x8 hi = *(const bf16x8*)(t + base + 64);
  float4 t0 = *(const float4*)(tb);
  float4 t1 = *(const float4*)(tb + 2);
  float4 t2 = *(const float4*)(tb + 4);
  float4 t3 = *(const float4*)(tb + 6);
  float cs[8], sn[8];
  cs[0]=t0.x; sn[0]=t0.y; cs[1]=t0.z; sn[1]=t0.w;
  cs[2]=t1.x; sn[2]=t1.y; cs[3]=t1.z; sn[3]=t1.w;
  cs[4]=t2.x; sn[4]=t2.y; cs[5]=t2.z; sn[5]=t2.w;
  cs[6]=t3.x; sn[6]=t3.y; cs[7]=t3.z; sn[7]=t3.w;
  bf16x8 olo, ohi;
#pragma unroll
  for (int j = 0; j < 8; ++j) {
    float a = (float)lo[j], b = (float)hi[j];
    olo[j] = (bf16)((a * cs[j] - b * sn[j]) * scale);
    ohi[j] = (bf16)((b * cs[j] + a * sn[j]) * scale);
  }
  *(bf16x8*)(t + base) = olo;
  *(bf16x8*)(t + base + 64) = ohi;
}

// ---------------- 256xBN 8-wave GEMM (m201-style) ----------------
// BM=256, BN=NJ*64 (NJ=3 -> 192, grid 16x16=256 exact for QKV). 8 waves (2M x 4N),
// wave out = 128 x (16*NJ). 2-buffer LDS. Per K-tile: 4 quadrant-phases; A staged
// ph0, B staged ph1; vmcnt(0) only at tile boundary.
// MODE 2: per-gc routing: <2048 -> C0=bq (2048); <2560 -> C1=bk (512); else C2=V^T.

template <int MODE, int NJ>
__global__ __launch_bounds__(512) void gemm256_k(const bf16* __restrict__ A,
                                                 const bf16* __restrict__ Bt,
                                                 void* __restrict__ C0,
                                                 void* __restrict__ C1,
                                                 void* __restrict__ C2,
                                                 int M, int N, int K) {
  extern __shared__ __align__(16) char smem[];
  constexpr int BUFSZ = 32768 + NJ * 8192;
  const int tid = threadIdx.x;
  const int lane = tid & 63;
  const int w = tid >> 6;
  const int wm = w >> 2;          // 0..1 (M half)
  const int wn = w & 3;           // 0..3 (N quarter)
  const int g16 = lane >> 4, c16 = lane & 15;
  const int row0 = blockIdx.y * 256;
  const int col0 = blockIdx.x * (NJ * 64);
  const int srow = tid >> 3;
  const int sslot = tid & 7;
  const int ldsw = w * 1024;

  // staging round r: r<4 -> A rows r*64.., r in [4,4+NJ) -> B rows (r-4)*64..
  auto stage = [&](int buf, int kt, int r) {
    int rr = (r < 4) ? r : r - 4;
    int row = rr * 64 + srow;
    int ss = sslot ^ (row & 7);
    const bf16* src = (r < 4) ? (A + (size_t)(row0 + row) * K)
                              : (Bt + (size_t)(col0 + row) * K);
    async_copy16(src + (kt << 6) + ss * 8,
                 smem + buf * BUFSZ + ((r < 4) ? 0 : 32768) + rr * 8192 + ldsw);
  };

  int offA[2][8], offB[2][NJ];
#pragma unroll
  for (int ks = 0; ks < 2; ++ks) {
#pragma unroll
    for (int i = 0; i < 8; ++i) {
      int ra = wm * 128 + i * 16 + c16;
      offA[ks][i] = ra * 128 + (((ks * 4 + g16) ^ (ra & 7)) << 4);
    }
#pragma unroll
    for (int j = 0; j < NJ; ++j) {
      int rb = wn * (16 * NJ) + j * 16 + c16;
      offB[ks][j] = 32768 + rb * 128 + (((ks * 4 + g16) ^ (rb & 7)) << 4);
    }
  }

  const f32x4 fz = {0.f, 0.f, 0.f, 0.f};
  f32x4 acc[8][NJ];
#pragma unroll
  for (int i = 0; i < 8; ++i)
#pragma unroll
    for (int j = 0; j < NJ; ++j) acc[i][j] = fz;

  const int nkt = K >> 6;
#pragma unroll
  for (int r = 0; r < 4 + NJ; ++r) stage(0, 0, r);
  asm volatile("s_waitcnt vmcnt(0)" ::: "memory");
  __builtin_amdgcn_s_barrier();

  for (int t = 0; t < nkt; ++t) {
    const char* Ab = smem + (t & 1) * BUFSZ;
    const bool pf = (t + 1 < nkt);
    const int nb = (t + 1) & 1;
    bf16x8 bfr[2][NJ];

    // ---- phase 0: quadrant m01; read all B + A m01; stage A rounds ----
    {
      bf16x8 af[2][2];
#pragma unroll
      for (int ks = 0; ks < 2; ++ks) {
#pragma unroll
        for (int j = 0; j < NJ; ++j) bfr[ks][j] = *(const bf16x8*)(Ab + offB[ks][j]);
        af[ks][0] = *(const bf16x8*)(Ab + offA[ks][0]);
        af[ks][1] = *(const bf16x8*)(Ab + offA[ks][1]);
      }
      if (pf) { stage(nb, t + 1, 0); stage(nb, t + 1, 1); stage(nb, t + 1, 2); stage(nb, t + 1, 3); }
      __builtin_amdgcn_s_barrier();
      asm volatile("s_waitcnt lgkmcnt(0)" ::: "memory");
      __builtin_amdgcn_sched_barrier(0);
      __builtin_amdgcn_s_setprio(1);
#pragma unroll
      for (int ks = 0; ks < 2; ++ks)
#pragma unroll
        for (int m = 0; m < 2; ++m)
#pragma unroll
          for (int j = 0; j < NJ; ++j)
            acc[m][j] = mfma16(af[ks][m], bfr[ks][j], acc[m][j]);
      __builtin_amdgcn_s_setprio(0);
      __builtin_amdgcn_sched_barrier(0);
      __builtin_amdgcn_s_barrier();
    }

    // ---- phases 1-3: quadrants m23 / m45 / m67 ----
#pragma unroll
    for (int q = 1; q < 4; ++q) {
      bf16x8 af[2][2];
#pragma unroll
      for (int ks = 0; ks < 2; ++ks) {
        af[ks][0] = *(const bf16x8*)(Ab + offA[ks][q * 2]);
        af[ks][1] = *(const bf16x8*)(Ab + offA[ks][q * 2 + 1]);
      }
      if (q == 1 && pf) {
#pragma unroll
        for (int r = 0; r < NJ; ++r) stage(nb, t + 1, 4 + r);
      }
      __builtin_amdgcn_s_barrier();
      asm volatile("s_waitcnt lgkmcnt(0)" ::: "memory");
      __builtin_amdgcn_sched_barrier(0);
      __builtin_amdgcn_s_setprio(1);
#pragma unroll
      for (int ks = 0; ks < 2; ++ks)
#pragma unroll
        for (int m = 0; m < 2; ++m)
#pragma unroll
          for (int j = 0; j < NJ; ++j)
            acc[q * 2 + m][j] = mfma16(af[ks][m], bfr[ks][j], acc[q * 2 + m][j]);
      __builtin_amdgcn_s_setprio(0);
      __builtin_amdgcn_sched_barrier(0);
      if (q == 3 && pf) asm volatile("s_waitcnt vmcnt(0)" ::: "memory");
      __builtin_amdgcn_s_barrier();
    }
  }

  // C/D mapping: col = lane&15, row = (lane>>4)*4 + reg
#pragma unroll
  for (int i = 0; i < 8; ++i) {
    int gr0 = row0 + wm * 128 + i * 16 + g16 * 4;
#pragma unroll
    for (int j = 0; j < NJ; ++j) {
      int gc = col0 + wn * (16 * NJ) + j * 16 + c16;
      if constexpr (MODE == 2) {
        if (gc < 2048) {
#pragma unroll
          for (int r = 0; r < 4; ++r)
            ((bf16*)C0)[(size_t)(gr0 + r) * 2048 + gc] = (bf16)acc[i][j][r];
        } else if (gc < 2560) {
#pragma unroll
          for (int r = 0; r < 4; ++r)
            ((bf16*)C1)[(size_t)(gr0 + r) * 512 + (gc - 2048)] = (bf16)acc[i][j][r];
        } else {
          int dv = gc - 2560;                 // 0..511
          int hkv = dv >> 7, d = dv & 127;
          size_t va = (((size_t)(gr0 >> 11) * NKV_ + hkv) * HD_ + d) * S_ + (gr0 & 2047);
          bf16x4 pk;
#pragma unroll
          for (int r = 0; r < 4; ++r) pk[r] = (bf16)acc[i][j][r];
          *(bf16x4*)((bf16*)C2 + va) = pk;
        }
      } else {
#pragma unroll
        for (int r = 0; r < 4; ++r) {
          if constexpr (MODE == 1)
            ((float*)C0)[(size_t)(gr0 + r) * N + gc] = acc[i][j][r];
          else
            ((bf16*)C0)[(size_t)(gr0 + r) * N + gc] = (bf16)acc[i][j][r];
        }
      }
    }
  }
}

// ---------------- 128x256 8-wave pipelined GEMM (O-proj: 256 blocks exact) ----------------

template <int MODE>
__global__ __launch_bounds__(512) void gemm8_k(const bf16* __restrict__ A,
                                               const bf16* __restrict__ Bt,
                                               void* __restrict__ C0,
                                               void* __restrict__ C1,
                                               void* __restrict__ C2,
                                               int M, int N, int K) {
  extern __shared__ __align__(16) char smem[];
  const int tid = threadIdx.x;
  const int lane = tid & 63;
  const int w = tid >> 6;
  const int wm = w >> 2;
  const int wn = w & 3;
  const int g16 = lane >> 4, c16 = lane & 15;
  const int row0 = blockIdx.y * 128;
  const int col0 = blockIdx.x * 256;
  const int srow = tid >> 3;
  const int sslot = tid & 7;
  const int ldsw = w * 1024;

  auto stageA = [&](int s, int kt, int r) {
    int row = r * 64 + srow;
    int ss = sslot ^ (row & 7);
    async_copy16(A + (size_t)(row0 + row) * K + (kt << 6) + ss * 8,
                 smem + s * 49152 + r * 8192 + ldsw);
  };
  auto stageB = [&](int s, int kt, int r) {
    int row = r * 64 + srow;
    int ss = sslot ^ (row & 7);
    async_copy16(Bt + (size_t)(col0 + row) * K + (kt << 6) + ss * 8,
                 smem + s * 49152 + 16384 + r * 8192 + ldsw);
  };

  int offA[2][4], offB[2][4];
#pragma unroll
  for (int ks = 0; ks < 2; ++ks) {
#pragma unroll
    for (int i = 0; i < 4; ++i) {
      int ra = wm * 64 + i * 16 + c16;
      offA[ks][i] = ra * 128 + (((ks * 4 + g16) ^ (ra & 7)) << 4);
      int rb = wn * 64 + i * 16 + c16;
      offB[ks][i] = rb * 128 + (((ks * 4 + g16) ^ (rb & 7)) << 4);
    }
  }

  const f32x4 fz = {0.f, 0.f, 0.f, 0.f};
  f32x4 acc[4][4];
#pragma unroll
  for (int i = 0; i < 4; ++i)
#pragma unroll
    for (int j = 0; j < 4; ++j) acc[i][j] = fz;

  const int nkt = K >> 6;
#pragma unroll
  for (int r = 0; r < 2; ++r) stageA(0, 0, r);
#pragma unroll
  for (int r = 0; r < 4; ++r) stageB(0, 0, r);
#pragma unroll
  for (int r = 0; r < 2; ++r) stageA(1, 1, r);
#pragma unroll
  for (int r = 0; r < 4; ++r) stageB(1, 1, r);
  asm volatile("s_waitcnt vmcnt(6)" ::: "memory");
  __builtin_amdgcn_s_barrier();

  int ct = 0, pt = 2;
  for (int t = 0; t < nkt; ++t) {
    const char* Ab = smem + ct * 49152;
    const char* Bb = Ab + 16384;
    const bool pf = (t + 2 < nkt);
    const int kpf = t + 2;
    bf16x8 af[4], bfr[4];

#pragma unroll
    for (int i = 0; i < 4; ++i) af[i] = *(const bf16x8*)(Ab + offA[0][i]);
#pragma unroll
    for (int j = 0; j < 4; ++j) bfr[j] = *(const bf16x8*)(Bb + offB[0][j]);
    if (pf) { stageA(pt, kpf, 0); stageA(pt, kpf, 1); stageB(pt, kpf, 0); }
    __builtin_amdgcn_s_barrier();
    asm volatile("s_waitcnt lgkmcnt(0)" ::: "memory");
    __builtin_amdgcn_sched_barrier(0);
    __builtin_amdgcn_s_setprio(1);
#pragma unroll
    for (int i = 0; i < 4; ++i)
#pragma unroll
      for (int j = 0; j < 4; ++j) acc[i][j] = mfma16(af[i], bfr[j], acc[i][j]);
    __builtin_amdgcn_s_setprio(0);
    __builtin_amdgcn_sched_barrier(0);
    __builtin_amdgcn_s_barrier();

#pragma unroll
    for (int i = 0; i < 4; ++i) af[i] = *(const bf16x8*)(Ab + offA[1][i]);
#pragma unroll
    for (int j = 0; j < 4; ++j) bfr[j] = *(const bf16x8*)(Bb + offB[1][j]);
    if (pf) { stageB(pt, kpf, 1); stageB(pt, kpf, 2); stageB(pt, kpf, 3); }
    if (pf) asm volatile("s_waitcnt vmcnt(6)" ::: "memory");
    else    asm volatile("s_waitcnt vmcnt(0)" ::: "memory");
    __builtin_amdgcn_s_barrier();
    asm volatile("s_waitcnt lgkmcnt(0)" ::: "memory");
    __builtin_amdgcn_sched_barrier(0);
    __builtin_amdgcn_s_setprio(1);
#pragma unroll
    for (int i = 0; i < 4; ++i)
#pragma unroll
      for (int j = 0; j < 4; ++j) acc[i][j] = mfma16(af[i], bfr[j], acc[i][j]);
    __builtin_amdgcn_s_setprio(0);
    __builtin_amdgcn_sched_barrier(0);
    __builtin_amdgcn_s_barrier();

    ct = (ct == 2) ? 0 : ct + 1;
    pt = (pt == 2) ? 0 : pt + 1;
  }

#pragma unroll
  for (int i = 0; i < 4; ++i) {
    int gr0 = row0 + wm * 64 + i * 16 + g16 * 4;
#pragma unroll
    for (int j = 0; j < 4; ++j) {
      int gc = col0 + wn * 64 + j * 16 + c16;
#pragma unroll
      for (int r = 0; r < 4; ++r) {
        if constexpr (MODE == 1)
          ((float*)C0)[(size_t)(gr0 + r) * N + gc] = acc[i][j][r];
        else
          ((bf16*)C0)[(size_t)(gr0 + r) * N + gc] = (bf16)acc[i][j][r];
      }
    }
  }
}

// ---------------- flash attention (causal, GQA) — T15 deferred-PV pipeline ----------------
// QBLK=128 (4 waves x 32 q-rows), KVBLK=64. Per iteration: QK(t) + PV(t-1) as one
// MFMA cluster, then softmax(t) -> pa. PV(t-1) accumulates BEFORE softmax(t)'s
// rescale (correct online-softmax order). Ks[2] (32KB) + Vt[3] (48KB) = 80KB,
// 2 blocks/CU. One barrier per tile.

__global__ __launch_bounds__(256, 2) void attn_fwd_k(const bf16* __restrict__ Qg,
                                                     const bf16* __restrict__ Kg,
                                                     const bf16* __restrict__ VTg,
                                                     bf16* __restrict__ Og) {
  __shared__ __align__(16) bf16 Ks[2][64 * 128];   // rows 256B (16 slots), swz slot^(row&7)
  __shared__ __align__(16) bf16 Vt[3][128 * 64];   // rows 128B (8 slots),  swz slot^(row&7)

  const int tid = threadIdx.x;
  const int lane = tid & 63;
  const int w = tid >> 6;
  const int g16 = lane >> 4;
  const int c16 = lane & 15;

  int bid = blockIdx.x;
  int rr_ = bid >> 5, bh = bid & 31;
  int qb = (rr_ < 8) ? (15 - rr_) : (rr_ - 8);
  const int b = bh >> 4;
  const int h = bh & 15;
  const int hkv = h >> 2;
  const int q0 = qb * 128;
  const int qw = q0 + w * 32;

  bf16x8 qf[2][4];
#pragma unroll
  for (int nq = 0; nq < 2; ++nq)
#pragma unroll
    for (int ksq = 0; ksq < 4; ++ksq)
      qf[nq][ksq] = *(const bf16x8*)(Qg + ((size_t)(b * S_ + qw + nq * 16 + c16) * NH_ + h) * HD_ + (ksq * 4 + g16) * 8);

  float m_run[2] = {-1e30f, -1e30f};
  float l_run[2] = {0.f, 0.f};
  const f32x4 fz = {0.f, 0.f, 0.f, 0.f};
  f32x4 acc[2][8];
#pragma unroll
  for (int nq = 0; nq < 2; ++nq)
#pragma unroll
    for (int dt = 0; dt < 8; ++dt) acc[nq][dt] = fz;

  const size_t kbase = ((size_t)b * S_ * NKV_ + hkv) * HD_;
  const size_t vbase = ((size_t)(b * NKV_ + hkv)) * HD_ * S_;

  auto stageK = [&](int buf, int kv0) {
#pragma unroll
    for (int rd = 0; rd < 4; ++rd) {
      int Lb = rd * 256 + w * 64;
      int row = (Lb + lane) >> 4;
      int ssl = (lane & 15) ^ (row & 7);
      async_copy16(Kg + kbase + (size_t)(kv0 + row) * (NKV_ * HD_) + ssl * 8,
                   (char*)&Ks[buf][0] + Lb * 16);
    }
  };
  auto stageV = [&](int buf, int kv0) {
#pragma unroll
    for (int rd = 0; rd < 4; ++rd) {
      int Lb = rd * 256 + w * 64;
      int row = (Lb + lane) >> 3;
      int ssl = (lane & 7) ^ (row & 7);
      async_copy16(VTg + vbase + (size_t)row * S_ + kv0 + ssl * 8,
                   (char*)&Vt[buf][0] + Lb * 16);
    }
  };

  const int ntiles = 2 * qb + 2;
  stageK(0, 0);
  stageV(0, 0);

  bf16x8 pa[2][2];          // persistent P fragments (tile t-1)
  bool pend = false;        // a PV is pending (wave-uniform)
  int vb_pend = 0;          // V buffer of pending tile (wave-uniform)
  int vbt = 0;              // V buffer of current tile t

  for (int t = 0; t < ntiles; ++t) {
    __syncthreads();        // drains vmcnt(0): K(t), V(t) staged; all waves done iter t-1
    int vbn = (vbt == 2) ? 0 : vbt + 1;
    if (t + 1 < ntiles) { stageK((t + 1) & 1, (t + 1) * 64); stageV(vbn, (t + 1) * 64); }
    const int kv0 = t * 64;
    const bool g = (kv0 <= qw + 31);

    f32x4 sc[2][4];
    if (g) {
      const char* KsC = (const char*)&Ks[t & 1][0];
#pragma unroll
      for (int nq = 0; nq < 2; ++nq)
#pragma unroll
        for (int mt = 0; mt < 4; ++mt) sc[nq][mt] = fz;

      __builtin_amdgcn_s_setprio(1);
#pragma unroll
      for (int ksq = 0; ksq < 4; ++ksq) {
        bf16x8 kf[4];
#pragma unroll
        for (int mt = 0; mt < 4; ++mt) {
          int gp = c16 >> 2, rp = c16 & 3;
          int blk = 8 * (mt >> 1) + 2 * gp + ((mt & 1) ^ (gp & 1));
          int row = blk * 4 + rp;
          kf[mt] = *(const bf16x8*)(KsC + row * 256 + (((ksq * 4 + g16) ^ (row & 7)) << 4));
        }
#pragma unroll
        for (int nq = 0; nq < 2; ++nq)
#pragma unroll
          for (int mt = 0; mt < 4; ++mt)
            sc[nq][mt] = mfma16(kf[mt], qf[nq][ksq], sc[nq][mt]);
      }
      __builtin_amdgcn_s_setprio(0);
    }

    // ---- deferred PV(t-1): accumulates BEFORE softmax(t)'s rescale ----
    if (pend) {
      const char* VtP = (const char*)&Vt[vb_pend][0];
      __builtin_amdgcn_s_setprio(1);
#pragma unroll
      for (int ks = 0; ks < 2; ++ks)
#pragma unroll
        for (int dt = 0; dt < 8; ++dt) {
          int rv = dt * 16 + c16;
          bf16x8 vf = *(const bf16x8*)(VtP + rv * 128 + (((ks * 4 + g16) ^ (rv & 7)) << 4));
          acc[0][dt] = mfma16(vf, pa[0][ks], acc[0][dt]);
          acc[1][dt] = mfma16(vf, pa[1][ks], acc[1][dt]);
        }
      __builtin_amdgcn_s_setprio(0);
      pend = false;
    }

    if (g) {
      // causal mask on partially-masked tiles
      if (kv0 + 63 > qw) {
#pragma unroll
        for (int nq = 0; nq < 2; ++nq) {
          int qa = qw + nq * 16 + c16;
#pragma unroll
          for (int mt = 0; mt < 4; ++mt) {
            int blk = 8 * (mt >> 1) + 2 * g16 + ((mt & 1) ^ (g16 & 1));
#pragma unroll
            for (int r = 0; r < 4; ++r) {
              int ka = kv0 + blk * 4 + r;
              if (ka > qa) sc[nq][mt][r] = -1e30f;
            }
          }
        }
      }

      // online softmax (base-2) with defer-max
      float mx[2];
#pragma unroll
      for (int nq = 0; nq < 2; ++nq) {
        float v = sc[nq][0][0];
#pragma unroll
        for (int mt = 0; mt < 4; ++mt)
#pragma unroll
          for (int r = 0; r < 4; ++r) v = fmaxf(v, sc[nq][mt][r]);
        v = fmaxf(v, __shfl_xor(v, 16));
        v = fmaxf(v, __shfl_xor(v, 32));
        mx[nq] = v;
      }
      if (__any((mx[0] > m_run[0] + 8.f) || (mx[1] > m_run[1] + 8.f))) {
#pragma unroll
        for (int nq = 0; nq < 2; ++nq) {
          float mn = fmaxf(m_run[nq], mx[nq]);
          float corr = exp2f(m_run[nq] - mn);
          m_run[nq] = mn;
          l_run[nq] *= corr;
#pragma unroll
          for (int dt = 0; dt < 8; ++dt) acc[nq][dt] *= corr;
        }
      }
#pragma unroll
      for (int nq = 0; nq < 2; ++nq) {
        float sum = 0.f;
#pragma unroll
        for (int mt = 0; mt < 4; ++mt)
#pragma unroll
          for (int r = 0; r < 4; ++r) {
            float p = exp2f(sc[nq][mt][r] - m_run[nq]);
            sc[nq][mt][r] = p;
            sum += p;
          }
        sum += __shfl_xor(sum, 16);
        sum += __shfl_xor(sum, 32);
        l_run[nq] += sum;
      }

      // P -> bf16 fragments, in-lane; becomes pending PV
#pragma unroll
      for (int nq = 0; nq < 2; ++nq)
#pragma unroll
        for (int ks = 0; ks < 2; ++ks) {
          f32x4 sA = (g16 & 1) ? sc[nq][2 * ks + 1] : sc[nq][2 * ks];
          f32x4 sB = (g16 & 1) ? sc[nq][2 * ks] : sc[nq][2 * ks + 1];
          bf16x8 tf;
          tf[0] = (bf16)sA[0]; tf[1] = (bf16)sA[1]; tf[2] = (bf16)sA[2]; tf[3] = (bf16)sA[3];
          tf[4] = (bf16)sB[0]; tf[5] = (bf16)sB[1]; tf[6] = (bf16)sB[2]; tf[7] = (bf16)sB[3];
          pa[nq][ks] = tf;
        }
      pend = true;
      vb_pend = vbt;
    }
    vbt = vbn;
  }

  // flush last pending PV (V(t_last) never overwritten: stages stopped)
  if (pend) {
    const char* VtP = (const char*)&Vt[vb_pend][0];
#pragma unroll
    for (int ks = 0; ks < 2; ++ks)
#pragma unroll
      for (int dt = 0; dt < 8; ++dt) {
        int rv = dt * 16 + c16;
        bf16x8 vf = *(const bf16x8*)(VtP + rv * 128 + (((ks * 4 + g16) ^ (rv & 7)) << 4));
        acc[0][dt] = mfma16(vf, pa[0][ks], acc[0][dt]);
        acc[1][dt] = mfma16(vf, pa[1][ks], acc[1][dt]);
      }
  }

#pragma unroll
  for (int nq = 0; nq < 2; ++nq) {
    float inv = 1.0f / l_run[nq];
    size_t base = ((size_t)(b * S_ + qw + nq * 16 + c16) * NH_ + h) * HD_ + g16 * 4;
#pragma unroll
    for (int dt = 0; dt < 8; ++dt) {
      bf16x4 ov;
#pragma unroll
      for (int r = 0; r < 4; ++r) ov[r] = (bf16)(acc[nq][dt][r] * inv);
      *(bf16x4*)(Og + base + dt * 16) = ov;
    }
  }
}

// ---------------- launcher ----------------

extern "C" void kernel_launch(void* const* d_in, const int* in_sizes, int n_in,
                              void* d_out, int out_size, void* d_ws, size_t ws_size,
                              hipStream_t stream) {
  const float* x  = (const float*)d_in[0];
  const int* pos  = (const int*)d_in[2];
  const float* Wq = (const float*)d_in[3];
  const float* Wk = (const float*)d_in[4];
  const float* Wv = (const float*)d_in[5];
  const float* Wo = (const float*)d_in[6];

  char* ws = (char*)d_ws;
  size_t off = 0;
  auto alloc = [&](size_t bytes) -> char* {
    char* p = ws + off;
    off += (bytes + 255) & ~(size_t)255;
    return p;
  };
  const size_t rows = (size_t)B_ * S_;
  bf16* xb    = (bf16*)alloc(rows * H_ * 2);
  bf16* bq    = (bf16*)alloc(rows * (NH_ * HD_) * 2);
  bf16* batt  = (bf16*)alloc(rows * (NH_ * HD_) * 2);
  bf16* WqkvT = (bf16*)alloc((size_t)3072 * H_ * 2);   // rows: Wq 0..2047 | Wk ..2559 | Wv ..3071
  bf16* WoT   = (bf16*)alloc((size_t)H_ * H_ * 2);
  bf16* bk    = (bf16*)alloc(rows * (NKV_ * HD_) * 2);
  bf16* VT    = (bf16*)alloc(rows * (NKV_ * HD_) * 2); // [b][hkv][d][S]
  float2* tab = (float2*)alloc((size_t)S_ * 64 * sizeof(float2));

  auto* fqkv = gemm256_k<2, 3>;
  auto* fo   = gemm8_k<1>;
  const int lds256 = 2 * (32768 + 3 * 8192);  // 114688
  const int lds8   = 3 * 49152;               // 147456
  bool big =
      (hipFuncSetAttribute((const void*)fqkv, hipFuncAttributeMaxDynamicSharedMemorySize, lds256) == hipSuccess) &&
      (hipFuncSetAttribute((const void*)fo, hipFuncAttributeMaxDynamicSharedMemorySize, lds8) == hipSuccess);

  // prep
  f32_to_bf16_k<<<(rows * H_) / (256 * 4), 256, 0, stream>>>(x, xb, rows * H_);
  transpose_all_k<<<10240, dim3(32, 8), 0, stream>>>(Wq, Wk, Wv, Wo, WqkvT, WoT);
  rope_table_k<<<(S_ * 64) / 256, 256, 0, stream>>>(tab);

  // fused QKV projection: 256x192 tiles, grid 16x16 = 256 blocks exact
  gemm256_k<2, 3><<<dim3(16, 16), 512, lds256, stream>>>(xb, WqkvT, bq, bk, VT, 4096, 3072, 2048);
  (void)big;

  // RoPE (vectorized): Q gets 1/sqrt(HD) * log2(e) folded in (exp2-domain softmax)
  rope_apply_v8_k<<<(4096 * NH_ * 8) / 256, 256, 0, stream>>>(bq, pos, tab, 4, 15, 0.12753102f);
  rope_apply_v8_k<<<(4096 * NKV_ * 8) / 256, 256, 0, stream>>>(bk, pos, tab, 2, 3, 1.0f);

  // attention
  attn_fwd_k<<<dim3(512), 256, 0, stream>>>(bq, bk, VT, batt);

  // output projection (f32 out): 128x256 tile, 8x32 = 256 blocks exact fit
  gemm8_k<1><<<dim3(8, 32), 512, lds8, stream>>>(batt, WoT, d_out, nullptr, nullptr, 4096, 2048, 2048);
}